// Round 4
// baseline (1872.573 us; speedup 1.0000x reference)
//
#include <hip/hip_runtime.h>
#include <hip/hip_bf16.h>

#define DD 64
#define KK 20
#define SLICES 32          // f32-fallback attention slicing
#define NSTRIP 625         // 10000 users / 16 per strip
#define ASLICE 8           // MFMA attention news slices
#define NCHUNK 313         // ceil(10000/32) 32-news chunks
#define ATSTRIDE 10016     // padded news stride of AT (d-major)

typedef __attribute__((ext_vector_type(8))) short short8;
typedef __attribute__((ext_vector_type(4))) float f32x4;

__device__ __forceinline__ unsigned short f2bf(float x) {
    union { __hip_bfloat16 h; unsigned short u; } cv;
    cv.h = __float2bfloat16(x);
    return cv.u;
}

// ---- dtype accessors (runtime-detected bf16 vs f32 path) ----
struct BF16Acc {
    static __device__ __forceinline__ float ld(const void* p, long i) {
        return __bfloat162float(((const __hip_bfloat16*)p)[i]);
    }
    static __device__ __forceinline__ void st(void* p, long i, float v) {
        ((__hip_bfloat16*)p)[i] = __float2bfloat16(v);
    }
};
struct F32Acc {
    static __device__ __forceinline__ float ld(const void* p, long i) {
        return ((const float*)p)[i];
    }
    static __device__ __forceinline__ void st(void* p, long i, float v) {
        ((float*)p)[i] = v;
    }
};

// ---- dtype detect (see R2 post-mortem): bf16 N(0,1) halves are all |x|<100 ----
__global__ void detect_kernel(const unsigned short* __restrict__ u, int* __restrict__ flag)
{
    if (threadIdx.x == 0 && blockIdx.x == 0) {
        int isbf = 1;
        for (int i = 0; i < 256; ++i) {
            float f = __uint_as_float(((unsigned)u[i]) << 16);
            if (!(fabsf(f) < 100.f)) isbf = 0;
        }
        *flag = isbf;
    }
}

// ---------------- stage 1: news / entity aggregation ----------------
template <typename Acc>
__device__ __forceinline__ void agg_body(
    const void* head_emb, const void* ent_emb, const void* rel_emb,
    const int* __restrict__ ent_idx, const int* __restrict__ rel_idx,
    float* out_f32, void* out_base, long out_elem_off, int N)
{
    int wave = threadIdx.x >> 6;
    int lane = threadIdx.x & 63;
    int n = blockIdx.x * 4 + wave;
    if (n >= N) return;

    float head = Acc::ld(head_emb, (long)n * DD + lane);

    float tail[KK], trp[KK];
    float s2 = 0.f;
#pragma unroll
    for (int k = 0; k < KK; ++k) {
        int e = ent_idx[n * KK + k];
        int r = rel_idx[n * KK + k];
        float rv = Acc::ld(rel_emb, (long)r * DD + lane);
        float tv = Acc::ld(ent_emb, (long)e * DD + lane);
        tail[k] = tv;
        trp[k] = tv * rv;
        s2 = fmaf(rv, rv, s2);
    }
    float hn = fabsf(head) * sqrtf(s2);

    float att[KK];
#pragma unroll
    for (int k = 0; k < KK; ++k) {
        float v = trp[k] * hn;
#pragma unroll
        for (int off = 32; off > 0; off >>= 1)
            v += __shfl_xor(v, off, 64);
        att[k] = v * v;
    }
    float mx = att[0];
#pragma unroll
    for (int k = 1; k < KK; ++k) mx = fmaxf(mx, att[k]);
    float den = 0.f;
#pragma unroll
    for (int k = 0; k < KK; ++k) { att[k] = __expf(att[k] - mx); den += att[k]; }
    float inv = 1.f / den;
    float o = 0.f;
#pragma unroll
    for (int k = 0; k < KK; ++k) o = fmaf(att[k], tail[k], o);
    o *= inv;

    Acc::st(out_base, out_elem_off + (long)n * DD + lane, o);
    if (out_f32) out_f32[(long)n * DD + lane] = o;
}

__global__ __launch_bounds__(256)
void agg_kernel(const void* head_emb, const void* ent_emb, const void* rel_emb,
                const int* ent_idx, const int* rel_idx,
                float* out_f32, void* out_base, long out_elem_off, int N,
                const int* __restrict__ flag)
{
    if (*flag) agg_body<BF16Acc>(head_emb, ent_emb, rel_emb, ent_idx, rel_idx, out_f32, out_base, out_elem_off, N);
    else       agg_body<F32Acc >(head_emb, ent_emb, rel_emb, ent_idx, rel_idx, out_f32, out_base, out_elem_off, N);
}

// ---------------- stage 1b: transpose newsagg f32 [10000][64] -> AT bf16 [64][10016] ----------------
// d-major V so PV MFMA B-frags load per-lane-contiguous 16B. cols >= 10000 zero-filled.
__global__ __launch_bounds__(256)
void transpose_kernel(const float* __restrict__ src, unsigned short* __restrict__ AT)
{
    __shared__ float T[128][65];                   // +1 pad: stride 65 banks
    int t = threadIdx.x;
    int nb = blockIdx.x * 128;                     // news window base
    const float4* s4 = (const float4*)src;
#pragma unroll
    for (int i = 0; i < 8; ++i) {
        int f = i * 256 + t;                       // 2048 float4 per tile
        int row = f >> 4;                          // 16 float4 per row
        int c4 = f & 15;
        int gr = nb + row;
        float4 v = make_float4(0.f, 0.f, 0.f, 0.f);
        if (gr < 10000) v = s4[(long)gr * 16 + c4];
        T[row][c4 * 4 + 0] = v.x;
        T[row][c4 * 4 + 1] = v.y;
        T[row][c4 * 4 + 2] = v.z;
        T[row][c4 * 4 + 3] = v.w;
    }
    __syncthreads();
    int d = t >> 2;                                // 0..63
    int seg = t & 3;                               // 0..3, 32 cols each
#pragma unroll
    for (int g = 0; g < 8; ++g) {                  // 8 groups of 4 cols
        int nl = seg * 32 + g * 4;
        int n = nb + nl;
        if (n + 3 < ATSTRIDE) {
            ushort4 o;
            o.x = f2bf(T[nl + 0][d]);
            o.y = f2bf(T[nl + 1][d]);
            o.z = f2bf(T[nl + 2][d]);
            o.w = f2bf(T[nl + 3][d]);
            *(ushort4*)(AT + (long)d * ATSTRIDE + n) = o;
        }
    }
}

// ---------------- stage 2: sparse segment sum ----------------
template <typename Acc>
__device__ __forceinline__ void scatter_body(
    const int* __restrict__ rows, const int* __restrict__ cols,
    const void* vals, const float* __restrict__ A, float* __restrict__ seg, int nnz)
{
    long t = (long)blockIdx.x * blockDim.x + threadIdx.x;
    int e = (int)(t >> 6);
    int d = (int)(t & 63);
    if (e >= nnz) return;
    int r = rows[e];
    int c = cols[e];
    float v = Acc::ld(vals, e) * A[(long)c * DD + d];
    atomicAdd(&seg[(long)r * DD + d], v);
}

__global__ __launch_bounds__(256)
void scatter_kernel(const int* rows, const int* cols, const void* vals,
                    const float* A, float* seg, int nnz, const int* __restrict__ flag)
{
    if (*flag) scatter_body<BF16Acc>(rows, cols, vals, A, seg, nnz);
    else       scatter_body<F32Acc >(rows, cols, vals, A, seg, nnz);
}

// ---------------- stage 3 fallback (f32 inputs): VALU attention ----------------
template <typename Acc>
__device__ __forceinline__ void attn_body(
    const void* user_emb, const float* __restrict__ A,
    float* __restrict__ num, float* __restrict__ den, int n_users, int n_news)
{
    int lane = threadIdx.x & 63;
    int wave_id = blockIdx.x * 4 + (threadIdx.x >> 6);
    int n_ublocks = (n_users + 63) >> 6;
    int ub    = wave_id % n_ublocks;
    int slice = wave_id / n_ublocks;
    if (slice >= SLICES) return;

    int u = ub * 64 + lane;
    bool valid = (u < n_users);
    int uc = valid ? u : 0;

    float ureg[DD];
#pragma unroll
    for (int i = 0; i < DD; ++i) ureg[i] = Acc::ld(user_emb, (long)uc * DD + i);

    float acc[DD];
#pragma unroll
    for (int d = 0; d < DD; ++d) acc[d] = 0.f;
    float l = 0.f;

    int chunk = (n_news + SLICES - 1) / SLICES;
    int n0 = slice * chunk;
    int n1 = min(n_news, n0 + chunk);

    for (int n = n0; n < n1; ++n) {
        const float4* __restrict__ ar = (const float4*)(A + (long)n * DD);
        float logit = 0.f;
#pragma unroll
        for (int i = 0; i < 16; ++i) {
            float4 av = ar[i];
            logit = fmaf(ureg[4 * i + 0], av.x, logit);
            logit = fmaf(ureg[4 * i + 1], av.y, logit);
            logit = fmaf(ureg[4 * i + 2], av.z, logit);
            logit = fmaf(ureg[4 * i + 3], av.w, logit);
        }
        logit = fminf(logit, 70.f);
        float p = __expf(logit);
        l += p;
#pragma unroll
        for (int i = 0; i < 16; ++i) {
            float4 av = ar[i];
            acc[4 * i + 0] = fmaf(p, av.x, acc[4 * i + 0]);
            acc[4 * i + 1] = fmaf(p, av.y, acc[4 * i + 1]);
            acc[4 * i + 2] = fmaf(p, av.z, acc[4 * i + 2]);
            acc[4 * i + 3] = fmaf(p, av.w, acc[4 * i + 3]);
        }
    }

    if (valid) {
        atomicAdd(&den[u], l);
        float* np_ = num + (long)u * DD;
#pragma unroll
        for (int d = 0; d < DD; ++d) atomicAdd(&np_[d], acc[d]);
    }
}

// ---------------- stage 3: MFMA flash attention (bf16 path) ----------------
// Per wave: 16-user strip x one news slice, 32-news chunks.
// QK: D[u][n] via mfma_16x16x32_bf16 (A-frag = U rows, B-frag = Abf rows).
// P: C-layout -> LDS -> A-layout (m120 pattern). PV: B-frag from d-major AT.
__global__ __launch_bounds__(256)
void attn_kernel(const void* user_emb, const short* __restrict__ Abf,
                 const short* __restrict__ ATbf, const float* __restrict__ Af32,
                 float* __restrict__ num, float* __restrict__ den,
                 const int* __restrict__ flag)
{
    __shared__ __align__(16) short Plds[4][16 * 32];
    if (!*flag) {          // f32 fallback
        attn_body<F32Acc>(user_emb, Af32, num, den, 10000, 10000);
        return;
    }
    int w = threadIdx.x >> 6;
    int lane = threadIdx.x & 63;
    int wid = blockIdx.x * 4 + w;
    if (wid >= NSTRIP * ASLICE) return;
    int strip = wid % NSTRIP;
    int slice = wid / NSTRIP;
    int quad = lane >> 4;
    int l15  = lane & 15;
    int user0 = strip * 16;

    const short* U = (const short*)user_emb;
    // A-frag: U[user0+l15][k = quad*8+j (+32)]
    short8 ua0 = *(const short8*)(U + ((long)(user0 + l15)) * 64 + quad * 8);
    short8 ua1 = *(const short8*)(U + ((long)(user0 + l15)) * 64 + 32 + quad * 8);

    f32x4 numC[4];
#pragma unroll
    for (int c = 0; c < 4; ++c) numC[c] = (f32x4){0.f, 0.f, 0.f, 0.f};
    float dena[4] = {0.f, 0.f, 0.f, 0.f};

    int c0 = slice * 40;
    int c1 = min(NCHUNK, c0 + 40);
    short* P = Plds[w];

    for (int ch = c0; ch < c1; ++ch) {
        int nb = ch * 32;
        // ---- QK: two 16-news tiles ----
        short8 blo0 = *(const short8*)(Abf + ((long)(nb + l15)) * 64 + quad * 8);
        short8 blo1 = *(const short8*)(Abf + ((long)(nb + l15)) * 64 + 32 + quad * 8);
        short8 bhi0 = *(const short8*)(Abf + ((long)(nb + 16 + l15)) * 64 + quad * 8);
        short8 bhi1 = *(const short8*)(Abf + ((long)(nb + 16 + l15)) * 64 + 32 + quad * 8);
        f32x4 z = {0.f, 0.f, 0.f, 0.f};
        f32x4 Llo = __builtin_amdgcn_mfma_f32_16x16x32_bf16(ua0, blo0, z, 0, 0, 0);
        Llo = __builtin_amdgcn_mfma_f32_16x16x32_bf16(ua1, blo1, Llo, 0, 0, 0);
        f32x4 Lhi = __builtin_amdgcn_mfma_f32_16x16x32_bf16(ua0, bhi0, z, 0, 0, 0);
        Lhi = __builtin_amdgcn_mfma_f32_16x16x32_bf16(ua1, bhi1, Lhi, 0, 0, 0);

        // ---- softmax (unnormalized; mask news >= 10000 on last chunk) ----
        bool vlo = (nb + l15) < 10000;
        bool vhi = (nb + 16 + l15) < 10000;
#pragma unroll
        for (int r = 0; r < 4; ++r) {
            float plo = vlo ? __expf(fminf(Llo[r], 70.f)) : 0.f;
            float phi = vhi ? __expf(fminf(Lhi[r], 70.f)) : 0.f;
            dena[r] += plo + phi;
            // C-layout: row(user_local)=quad*4+r, col(news_local)=l15 (+16 hi)
            P[(quad * 4 + r) * 32 + l15]      = (short)f2bf(plo);
            P[(quad * 4 + r) * 32 + 16 + l15] = (short)f2bf(phi);
        }
        // ---- PV: P A-frag from LDS, V B-frags from d-major AT ----
        short8 ap = *(const short8*)(P + l15 * 32 + quad * 8);
#pragma unroll
        for (int c = 0; c < 4; ++c) {
            short8 vb = *(const short8*)(ATbf + ((long)(16 * c + l15)) * ATSTRIDE + nb + quad * 8);
            numC[c] = __builtin_amdgcn_mfma_f32_16x16x32_bf16(ap, vb, numC[c], 0, 0, 0);
        }
    }

    // den: butterfly over the 16 news-lanes within each quad
#pragma unroll
    for (int r = 0; r < 4; ++r) {
#pragma unroll
        for (int m = 1; m < 16; m <<= 1)
            dena[r] += __shfl_xor(dena[r], m, 64);
    }
    if (l15 == 0) {
#pragma unroll
        for (int r = 0; r < 4; ++r)
            atomicAdd(&den[user0 + quad * 4 + r], dena[r]);
    }
#pragma unroll
    for (int c = 0; c < 4; ++c)
#pragma unroll
        for (int r = 0; r < 4; ++r)
            atomicAdd(&num[(long)(user0 + quad * 4 + r) * 64 + c * 16 + l15], numC[c][r]);
}

// ---------------- stage 4: final combine ----------------
template <typename Acc>
__device__ __forceinline__ void final_body(
    const float* __restrict__ seg, const float* __restrict__ num,
    const float* __restrict__ den, void* out_base, long out_elem_off, int n_users)
{
    int t = blockIdx.x * 256 + threadIdx.x;
    if (t >= n_users * DD) return;
    int u = t >> 6;
    float s = seg[t];
    float o2 = num[t] / den[u];
    Acc::st(out_base, out_elem_off + t, fmaf(s, o2, s));
}

__global__ __launch_bounds__(256)
void final_kernel(const float* seg, const float* num, const float* den,
                  void* out_base, long out_elem_off, int n_users, const int* __restrict__ flag)
{
    if (*flag) final_body<BF16Acc>(seg, num, den, out_base, out_elem_off, n_users);
    else       final_body<F32Acc >(seg, num, den, out_base, out_elem_off, n_users);
}

extern "C" void kernel_launch(void* const* d_in, const int* in_sizes, int n_in,
                              void* d_out, int out_size, void* d_ws, size_t ws_size,
                              hipStream_t stream)
{
    const void* user_emb  = d_in[0];
    const void* news_emb  = d_in[1];
    const void* ent_emb   = d_in[2];
    const void* rel_emb   = d_in[3];
    const int* news_entities   = (const int*)d_in[4];
    const int* news_relations  = (const int*)d_in[5];
    const int* neigh_entities  = (const int*)d_in[6];
    const int* neigh_relations = (const int*)d_in[7];
    const int* interact_rows   = (const int*)d_in[8];
    const int* interact_cols   = (const int*)d_in[9];
    const void* interact_vals  = d_in[10];

    const int NU = 10000, NN = 10000, NE = 100000, NNZ = 500000;
    const long OFF_ENT  = 640000;
    const long OFF_USER = 7040000;

    // fp32 scratch inside the entity-output region of d_out (bytes [1.28M,14.08M) in bf16 mode).
    float* scratch = (float*)((char*)d_out + 2560000);
    float* newsagg = scratch;                        // 640000 f32
    float* seg     = scratch + 640000;               // 640000 f32
    float* num     = scratch + 1280000;              // 640000 f32
    float* den     = scratch + 1920000;              // 10240 f32
    int*   flag    = (int*)(scratch + 1930240);
    unsigned short* ATbf = (unsigned short*)(scratch + 1930244);  // 64*10016 bf16 = 1.28MB, 16B-aligned
    // scratch end: 2.56MB + 7.72MB + 1.28MB = 11.57MB < 14.08MB (bf16 entity region end)

    detect_kernel<<<1, 64, 0, stream>>>((const unsigned short*)user_emb, flag);
    hipMemsetAsync(seg, 0, (size_t)(640000 + 640000 + 10240) * sizeof(float), stream);

    // 1) news aggregation -> out[0] (bf16 = QK/V matrix) + newsagg f32
    agg_kernel<<<NN / 4, 256, 0, stream>>>(news_emb, ent_emb, rel_emb,
                                           news_entities, news_relations,
                                           newsagg, d_out, 0L, NN, flag);
    // 1b) d-major bf16 transpose for PV B-frags
    transpose_kernel<<<(NN + 127) / 128, 256, 0, stream>>>(newsagg, ATbf);
    // 2) sparse segment-sum -> seg
    scatter_kernel<<<(NNZ * 64) / 256, 256, 0, stream>>>(interact_rows, interact_cols,
                                                         interact_vals, newsagg, seg, NNZ, flag);
    // 3) MFMA flash attention partials -> num, den (f32 VALU fallback if flag==0)
    attn_kernel<<<1280, 256, 0, stream>>>(user_emb, (const short*)d_out, (const short*)ATbf,
                                          newsagg, num, den, flag);
    // 4) user output
    final_kernel<<<(NU * DD + 255) / 256, 256, 0, stream>>>(seg, num, den, d_out, OFF_USER, NU, flag);
    // 5) entity aggregation LAST — overwrites scratch with output 1
    agg_kernel<<<NE / 4, 256, 0, stream>>>(ent_emb, ent_emb, rel_emb,
                                           neigh_entities, neigh_relations,
                                           nullptr, d_out, OFF_ENT, NE, flag);
}

// Round 5
// 682.872 us; speedup vs baseline: 2.7422x; 2.7422x over previous
//
#include <hip/hip_runtime.h>
#include <hip/hip_bf16.h>

// All float tensors are fp32 (verified R1-R4: forced-bf16 reads -> NaN;
// R3/R4 passed exclusively via F32 paths; reference file says float32).

#define DD 64
#define KK 20
#define NCHUNK 313        // ceil(10000/32) 32-news chunks
#define ATSTRIDE 10016    // padded news stride of d-major V
#define PSTRIDE 40        // P LDS row stride (shorts): breaks bank aliasing

typedef __attribute__((ext_vector_type(8))) short short8;
typedef __attribute__((ext_vector_type(4))) float f32x4;

__device__ __forceinline__ unsigned short f2bf(float x) {
    union { __hip_bfloat16 h; unsigned short u; } cv;
    cv.h = __float2bfloat16(x);
    return cv.u;
}
__device__ __forceinline__ float bfu2f(unsigned short u) {
    return __uint_as_float(((unsigned)u) << 16);
}
#define MFMA16(a, b, c) __builtin_amdgcn_mfma_f32_16x16x32_bf16((a), (b), (c), 0, 0, 0)

// ---------------- stage 1: news / entity aggregation (fp32) ----------------
// one wave per row n; lane = d
__global__ __launch_bounds__(256)
void agg_kernel(const float* __restrict__ head_emb, const float* __restrict__ ent_emb,
                const float* __restrict__ rel_emb,
                const int* __restrict__ ent_idx, const int* __restrict__ rel_idx,
                float* __restrict__ outp, int N)
{
    int wave = threadIdx.x >> 6;
    int lane = threadIdx.x & 63;
    int n = blockIdx.x * 4 + wave;
    if (n >= N) return;

    float head = head_emb[(long)n * DD + lane];

    float tail[KK], trp[KK];
    float s2 = 0.f;
#pragma unroll
    for (int k = 0; k < KK; ++k) {
        int e = ent_idx[n * KK + k];
        int r = rel_idx[n * KK + k];
        float rv = rel_emb[(long)r * DD + lane];
        float tv = ent_emb[(long)e * DD + lane];
        tail[k] = tv;
        trp[k] = tv * rv;
        s2 = fmaf(rv, rv, s2);
    }
    float hn = fabsf(head) * sqrtf(s2);   // ref's axis=1 norm

    float att[KK];
#pragma unroll
    for (int k = 0; k < KK; ++k) {
        float v = trp[k] * hn;
#pragma unroll
        for (int off = 32; off > 0; off >>= 1)
            v += __shfl_xor(v, off, 64);
        att[k] = v * v;                   // reference squares the logit
    }
    float mx = att[0];
#pragma unroll
    for (int k = 1; k < KK; ++k) mx = fmaxf(mx, att[k]);
    float den = 0.f;
#pragma unroll
    for (int k = 0; k < KK; ++k) { att[k] = __expf(att[k] - mx); den += att[k]; }
    float inv = 1.f / den;
    float o = 0.f;
#pragma unroll
    for (int k = 0; k < KK; ++k) o = fmaf(att[k], tail[k], o);
    outp[(long)n * DD + lane] = o * inv;
}

// ---------------- stage 1b: split fp32 -> bf16 hi + bf16 lo (row-major) ----------------
__global__ __launch_bounds__(256)
void split_kernel(const float* __restrict__ src, unsigned short* __restrict__ hi,
                  unsigned short* __restrict__ lo, int n_src, int n_total)
{
    int t = blockIdx.x * 256 + threadIdx.x;
    if (t >= n_total) return;
    float v = (t < n_src) ? src[t] : 0.f;   // zero-pad rows >= 10000
    unsigned short h = f2bf(v);
    hi[t] = h;
    lo[t] = f2bf(v - bfu2f(h));
}

// ---------------- stage 1c: transpose+split newsagg [10000][64] -> AT{hi,lo} [64][10016] ----------------
__global__ __launch_bounds__(256)
void transpose_split_kernel(const float* __restrict__ src,
                            unsigned short* __restrict__ AThi,
                            unsigned short* __restrict__ ATlo)
{
    __shared__ float T[128][65];
    int t = threadIdx.x;
    int nb = blockIdx.x * 128;
    const float4* s4 = (const float4*)src;
#pragma unroll
    for (int i = 0; i < 8; ++i) {
        int f = i * 256 + t;
        int row = f >> 4;
        int c4 = f & 15;
        int gr = nb + row;
        float4 v = make_float4(0.f, 0.f, 0.f, 0.f);
        if (gr < 10000) v = s4[(long)gr * 16 + c4];
        T[row][c4 * 4 + 0] = v.x;
        T[row][c4 * 4 + 1] = v.y;
        T[row][c4 * 4 + 2] = v.z;
        T[row][c4 * 4 + 3] = v.w;
    }
    __syncthreads();
    int d = t >> 2;
    int seg = t & 3;
#pragma unroll
    for (int g = 0; g < 8; ++g) {
        int nl = seg * 32 + g * 4;
        int n = nb + nl;
        if (n + 3 < ATSTRIDE) {
            ushort4 oh, ol;
            float v0 = T[nl + 0][d], v1 = T[nl + 1][d], v2 = T[nl + 2][d], v3 = T[nl + 3][d];
            oh.x = f2bf(v0); ol.x = f2bf(v0 - bfu2f(oh.x));
            oh.y = f2bf(v1); ol.y = f2bf(v1 - bfu2f(oh.y));
            oh.z = f2bf(v2); ol.z = f2bf(v2 - bfu2f(oh.z));
            oh.w = f2bf(v3); ol.w = f2bf(v3 - bfu2f(oh.w));
            *(ushort4*)(AThi + (long)d * ATSTRIDE + n) = oh;
            *(ushort4*)(ATlo + (long)d * ATSTRIDE + n) = ol;
        }
    }
}

// ---------------- stage 2: sparse segment sum (fp32) ----------------
__global__ __launch_bounds__(256)
void scatter_kernel(const int* __restrict__ rows, const int* __restrict__ cols,
                    const float* __restrict__ vals, const float* __restrict__ A,
                    float* __restrict__ seg, int nnz)
{
    long t = (long)blockIdx.x * blockDim.x + threadIdx.x;
    int e = (int)(t >> 6);
    int d = (int)(t & 63);
    if (e >= nnz) return;
    int r = rows[e];
    int c = cols[e];
    float v = vals[e] * A[(long)c * DD + d];
    atomicAdd(&seg[(long)r * DD + d], v);
}

// ---------------- stage 3: split-bf16 MFMA flash attention ----------------
// block = one 16-user strip; 4 waves round-robin over 32-news chunks.
// QK = Uhi.Bhi + Uhi.Blo + Ulo.Bhi (logit err ~2^-17). p=exp(logit) unnorm.
// den sums the bf16-ROUNDED p so P-quantization cancels num/den at peaks.
// PV = Pbf.(AThi) + Pbf.(ATlo). Block-level LDS reduce -> plain stores.
__global__ __launch_bounds__(256)
void attn_kernel(const unsigned short* __restrict__ Uhi, const unsigned short* __restrict__ Ulo,
                 const unsigned short* __restrict__ Bhi, const unsigned short* __restrict__ Blo,
                 const unsigned short* __restrict__ AThi, const unsigned short* __restrict__ ATlo,
                 float* __restrict__ num, float* __restrict__ den)
{
    __shared__ __align__(16) short P[4][16 * PSTRIDE];
    __shared__ float RN[4][16][65];    // +1 pad: spread banks
    __shared__ float RD[4][16];

    int w = threadIdx.x >> 6;
    int lane = threadIdx.x & 63;
    int quad = lane >> 4;
    int l15 = lane & 15;
    int user0 = blockIdx.x * 16;

    // A-frags: U[user0+l15][k = quad*8+j (+32)]  (hi and lo planes)
    const short* uh = (const short*)Uhi + ((long)(user0 + l15)) * 64;
    const short* ul = (const short*)Ulo + ((long)(user0 + l15)) * 64;
    short8 uh0 = *(const short8*)(uh + quad * 8);
    short8 uh1 = *(const short8*)(uh + 32 + quad * 8);
    short8 ul0 = *(const short8*)(ul + quad * 8);
    short8 ul1 = *(const short8*)(ul + 32 + quad * 8);

    f32x4 numC[4];
#pragma unroll
    for (int c = 0; c < 4; ++c) numC[c] = (f32x4){0.f, 0.f, 0.f, 0.f};
    float dena[4] = {0.f, 0.f, 0.f, 0.f};
    short* Pw = P[w];

    for (int ch = w; ch < NCHUNK; ch += 4) {
        int nb = ch * 32;
        // ---- QK B-frags: rows nb+l15 (lo tile) and nb+16+l15 (hi tile) ----
        const short* bh = (const short*)Bhi + ((long)(nb + l15)) * 64;
        const short* bl = (const short*)Blo + ((long)(nb + l15)) * 64;
        short8 h00 = *(const short8*)(bh + quad * 8);
        short8 h01 = *(const short8*)(bh + 32 + quad * 8);
        short8 h10 = *(const short8*)(bh + 16 * 64 + quad * 8);
        short8 h11 = *(const short8*)(bh + 16 * 64 + 32 + quad * 8);
        short8 l00 = *(const short8*)(bl + quad * 8);
        short8 l01 = *(const short8*)(bl + 32 + quad * 8);
        short8 l10 = *(const short8*)(bl + 16 * 64 + quad * 8);
        short8 l11 = *(const short8*)(bl + 16 * 64 + 32 + quad * 8);

        f32x4 z = {0.f, 0.f, 0.f, 0.f};
        f32x4 Llo = MFMA16(uh0, h00, z);
        Llo = MFMA16(uh1, h01, Llo);
        Llo = MFMA16(uh0, l00, Llo);
        Llo = MFMA16(uh1, l01, Llo);
        Llo = MFMA16(ul0, h00, Llo);
        Llo = MFMA16(ul1, h01, Llo);
        f32x4 Lhi = MFMA16(uh0, h10, z);
        Lhi = MFMA16(uh1, h11, Lhi);
        Lhi = MFMA16(uh0, l10, Lhi);
        Lhi = MFMA16(uh1, l11, Lhi);
        Lhi = MFMA16(ul0, h10, Lhi);
        Lhi = MFMA16(ul1, h11, Lhi);

        // ---- softmax weights (unnormalized; mask news >= 10000) ----
        bool vlo = (nb + l15) < 10000;
        bool vhi = (nb + 16 + l15) < 10000;
#pragma unroll
        for (int r = 0; r < 4; ++r) {
            float plo = vlo ? __expf(fminf(Llo[r], 70.f)) : 0.f;
            float phi = vhi ? __expf(fminf(Lhi[r], 70.f)) : 0.f;
            unsigned short qlo = f2bf(plo), qhi = f2bf(phi);
            // C-layout -> LDS: row(user_local)=quad*4+r, col(news_local)=l15 (+16)
            Pw[(quad * 4 + r) * PSTRIDE + l15] = (short)qlo;
            Pw[(quad * 4 + r) * PSTRIDE + 16 + l15] = (short)qhi;
            dena[r] += bfu2f(qlo) + bfu2f(qhi);
        }
        // ---- PV: P A-frag from LDS (m120 layout swap), V B-frags from d-major AT ----
        short8 ap = *(const short8*)(Pw + l15 * PSTRIDE + quad * 8);
#pragma unroll
        for (int c = 0; c < 4; ++c) {
            const short* ath = (const short*)AThi + ((long)(16 * c + l15)) * ATSTRIDE + nb + quad * 8;
            const short* atl = (const short*)ATlo + ((long)(16 * c + l15)) * ATSTRIDE + nb + quad * 8;
            short8 vh = *(const short8*)ath;
            short8 vl = *(const short8*)atl;
            numC[c] = MFMA16(ap, vh, numC[c]);
            numC[c] = MFMA16(ap, vl, numC[c]);
        }
    }

    // den: butterfly over the 16 news-lanes (l15) within each quad
#pragma unroll
    for (int r = 0; r < 4; ++r) {
#pragma unroll
        for (int m = 1; m < 16; m <<= 1)
            dena[r] += __shfl_xor(dena[r], m, 64);
    }
    if (l15 == 0) {
#pragma unroll
        for (int r = 0; r < 4; ++r) RD[w][quad * 4 + r] = dena[r];
    }
#pragma unroll
    for (int c = 0; c < 4; ++c)
#pragma unroll
        for (int r = 0; r < 4; ++r)
            RN[w][quad * 4 + r][c * 16 + l15] = numC[c][r];
    __syncthreads();

    // cross-wave reduce -> plain global stores (no atomics)
    int t = threadIdx.x;
#pragma unroll
    for (int i = 0; i < 4; ++i) {
        int idx = i * 256 + t;
        int u = idx >> 6, d = idx & 63;
        float s = RN[0][u][d] + RN[1][u][d] + RN[2][u][d] + RN[3][u][d];
        num[(long)(user0 + u) * DD + d] = s;
    }
    if (t < 16)
        den[user0 + t] = RD[0][t] + RD[1][t] + RD[2][t] + RD[3][t];
}

// ---------------- stage 4: final combine (fp32 out) ----------------
__global__ __launch_bounds__(256)
void final_kernel(const float* __restrict__ seg, const float* __restrict__ num,
                  const float* __restrict__ den, float* __restrict__ out, int n_users)
{
    int t = blockIdx.x * 256 + threadIdx.x;
    if (t >= n_users * DD) return;
    int u = t >> 6;
    float s = seg[t];
    float o2 = num[t] / den[u];
    out[t] = fmaf(s, o2, s);             // seg + (score@A)*seg
}

extern "C" void kernel_launch(void* const* d_in, const int* in_sizes, int n_in,
                              void* d_out, int out_size, void* d_ws, size_t ws_size,
                              hipStream_t stream)
{
    const float* user_emb = (const float*)d_in[0];
    const float* news_emb = (const float*)d_in[1];
    const float* ent_emb  = (const float*)d_in[2];
    const float* rel_emb  = (const float*)d_in[3];
    const int* news_entities   = (const int*)d_in[4];
    const int* news_relations  = (const int*)d_in[5];
    const int* neigh_entities  = (const int*)d_in[6];
    const int* neigh_relations = (const int*)d_in[7];
    const int* interact_rows   = (const int*)d_in[8];
    const int* interact_cols   = (const int*)d_in[9];
    const float* interact_vals = (const float*)d_in[10];

    const int NU = 10000, NN = 10000, NE = 100000, NNZ = 500000;

    float* out_news = (float*)d_out;                 // [0, 2.56MB) — also the Q/K/V source
    float* out_ent  = out_news + (long)NN * DD;      // [2.56MB, 28.16MB)
    float* out_user = out_ent + (long)NE * DD;       // [28.16MB, 30.72MB)

    // Scratch inside the entity-output region (25.6MB; we use ~12.9MB).
    // Entity agg runs LAST and overwrites it. No d_ws use.
    float* seg = out_ent;                            // 640000 f32
    float* num = seg + 640000;                       // 640000 f32
    float* den = num + 640000;                       // 10240 f32
    unsigned short* Uhi  = (unsigned short*)(den + 10240);   // 640000 u16
    unsigned short* Ulo  = Uhi + 640000;
    unsigned short* Bhi  = Ulo + 640000;             // 641024 u16 (10016 rows)
    unsigned short* Blo  = Bhi + 641024;
    unsigned short* AThi = Blo + 641024;             // 64*10016 u16
    unsigned short* ATlo = AThi + 641024;
    // end: 2.56M*3 + 40960 + 2*1.28M + 4*1.282MB ≈ 15.4MB < 25.6MB ✓

    // seg is the only scratch that needs zeroing (scatter atomics)
    hipMemsetAsync(seg, 0, (size_t)640000 * sizeof(float), stream);

    // 1) news aggregation -> output 0 (also attention K/V source)
    agg_kernel<<<NN / 4, 256, 0, stream>>>(news_emb, ent_emb, rel_emb,
                                           news_entities, news_relations, out_news, NN);
    // 1b) bf16 hi/lo planes: U rows, B rows (padded to 10016), d-major AT
    split_kernel<<<2500, 256, 0, stream>>>(user_emb, Uhi, Ulo, NU * DD, NU * DD);
    split_kernel<<<2504, 256, 0, stream>>>(out_news, Bhi, Blo, NN * DD, 10016 * DD);
    transpose_split_kernel<<<(NN + 127) / 128, 256, 0, stream>>>(out_news, AThi, ATlo);
    // 2) sparse segment-sum -> seg
    scatter_kernel<<<(NNZ * 64) / 256, 256, 0, stream>>>(interact_rows, interact_cols,
                                                         interact_vals, out_news, seg, NNZ);
    // 3) MFMA attention partials -> num, den (one block per 16-user strip)
    attn_kernel<<<NU / 16, 256, 0, stream>>>(Uhi, Ulo, Bhi, Blo, AThi, ATlo, num, den);
    // 4) user output
    final_kernel<<<(NU * DD + 255) / 256, 256, 0, stream>>>(seg, num, den, out_user, NU);
    // 5) entity aggregation LAST — overwrites scratch with output 1
    agg_kernel<<<NE / 4, 256, 0, stream>>>(ent_emb, ent_emb, rel_emb,
                                           neigh_entities, neigh_relations, out_ent, NE);
}

// Round 6
// 637.921 us; speedup vs baseline: 2.9354x; 1.0705x over previous
//
#include <hip/hip_runtime.h>
#include <hip/hip_bf16.h>

// All float tensors are fp32 (verified R1-R5).

#define DD 64
#define KK 20
#define NCHUNK 313        // ceil(10000/32) 32-news chunks
#define NS 8              // news slices for attention occupancy
#define ATSTRIDE 10016    // padded news stride of d-major V
#define PSTRIDE 40        // P LDS row stride (shorts)

typedef __attribute__((ext_vector_type(8))) short short8;
typedef __attribute__((ext_vector_type(4))) float f32x4;

__device__ __forceinline__ unsigned short f2bf(float x) {
    union { __hip_bfloat16 h; unsigned short u; } cv;
    cv.h = __float2bfloat16(x);
    return cv.u;
}
__device__ __forceinline__ float bfu2f(unsigned short u) {
    return __uint_as_float(((unsigned)u) << 16);
}
#define MFMA16(a, b, c) __builtin_amdgcn_mfma_f32_16x16x32_bf16((a), (b), (c), 0, 0, 0)

// ---------------- stage 1: news / entity aggregation (fp32) ----------------
__global__ __launch_bounds__(256)
void agg_kernel(const float* __restrict__ head_emb, const float* __restrict__ ent_emb,
                const float* __restrict__ rel_emb,
                const int* __restrict__ ent_idx, const int* __restrict__ rel_idx,
                float* __restrict__ outp, int N)
{
    int wave = threadIdx.x >> 6;
    int lane = threadIdx.x & 63;
    int n = blockIdx.x * 4 + wave;
    if (n >= N) return;

    float head = head_emb[(long)n * DD + lane];

    float tail[KK], trp[KK];
    float s2 = 0.f;
#pragma unroll
    for (int k = 0; k < KK; ++k) {
        int e = ent_idx[n * KK + k];
        int r = rel_idx[n * KK + k];
        float rv = rel_emb[(long)r * DD + lane];
        float tv = ent_emb[(long)e * DD + lane];
        tail[k] = tv;
        trp[k] = tv * rv;
        s2 = fmaf(rv, rv, s2);
    }
    float hn = fabsf(head) * sqrtf(s2);   // ref's axis=1 norm

    float att[KK];
#pragma unroll
    for (int k = 0; k < KK; ++k) {
        float v = trp[k] * hn;
#pragma unroll
        for (int off = 32; off > 0; off >>= 1)
            v += __shfl_xor(v, off, 64);
        att[k] = v * v;
    }
    float mx = att[0];
#pragma unroll
    for (int k = 1; k < KK; ++k) mx = fmaxf(mx, att[k]);
    float den = 0.f;
#pragma unroll
    for (int k = 0; k < KK; ++k) { att[k] = __expf(att[k] - mx); den += att[k]; }
    float inv = 1.f / den;
    float o = 0.f;
#pragma unroll
    for (int k = 0; k < KK; ++k) o = fmaf(att[k], tail[k], o);
    outp[(long)n * DD + lane] = o * inv;
}

// ---------------- stage 1b: split fp32 -> bf16 hi + lo (row-major) ----------------
__global__ __launch_bounds__(256)
void split_kernel(const float* __restrict__ src, unsigned short* __restrict__ hi,
                  unsigned short* __restrict__ lo, int n_src, int n_total)
{
    int t = blockIdx.x * 256 + threadIdx.x;
    if (t >= n_total) return;
    float v = (t < n_src) ? src[t] : 0.f;
    unsigned short h = f2bf(v);
    hi[t] = h;
    lo[t] = f2bf(v - bfu2f(h));
}

// ---------------- stage 1c: transpose newsagg [10000][64] -> AThi bf16 [64][10016] ----------------
__global__ __launch_bounds__(256)
void transpose_kernel(const float* __restrict__ src, unsigned short* __restrict__ AThi)
{
    __shared__ float T[128][65];
    int t = threadIdx.x;
    int nb = blockIdx.x * 128;
    const float4* s4 = (const float4*)src;
#pragma unroll
    for (int i = 0; i < 8; ++i) {
        int f = i * 256 + t;
        int row = f >> 4;
        int c4 = f & 15;
        int gr = nb + row;
        float4 v = make_float4(0.f, 0.f, 0.f, 0.f);
        if (gr < 10000) v = s4[(long)gr * 16 + c4];
        T[row][c4 * 4 + 0] = v.x;
        T[row][c4 * 4 + 1] = v.y;
        T[row][c4 * 4 + 2] = v.z;
        T[row][c4 * 4 + 3] = v.w;
    }
    __syncthreads();
    int d = t >> 2;
    int seg = t & 3;
#pragma unroll
    for (int g = 0; g < 8; ++g) {
        int nl = seg * 32 + g * 4;
        int n = nb + nl;
        if (n + 3 < ATSTRIDE) {
            ushort4 oh;
            oh.x = f2bf(T[nl + 0][d]);
            oh.y = f2bf(T[nl + 1][d]);
            oh.z = f2bf(T[nl + 2][d]);
            oh.w = f2bf(T[nl + 3][d]);
            *(ushort4*)(AThi + (long)d * ATSTRIDE + n) = oh;
        }
    }
}

// ---------------- stage 2: segment-sum via CSR (hist/scan/fill/gather) ----------------
__global__ __launch_bounds__(256)
void hist_kernel(const int* __restrict__ rows, int* __restrict__ cnt, int nnz)
{
    int e = blockIdx.x * 256 + threadIdx.x;
    if (e < nnz) atomicAdd(&cnt[rows[e]], 1);
}

// single block; 256 threads x 40 rows = 10240 >= 10001 needed
__global__ __launch_bounds__(256)
void scan_kernel(const int* __restrict__ cnt, int* __restrict__ offs, int* __restrict__ cur)
{
    __shared__ int ssum[256];
    int t = threadIdx.x;
    int loc[40];
    int s = 0;
#pragma unroll
    for (int i = 0; i < 40; ++i) { loc[i] = s; s += cnt[t * 40 + i]; }
    ssum[t] = s;
    __syncthreads();
    int val = s;
    for (int off = 1; off < 256; off <<= 1) {
        int v = (t >= off) ? ssum[t - off] : 0;
        __syncthreads();
        val += v;
        ssum[t] = val;
        __syncthreads();
    }
    int excl = val - s;
#pragma unroll
    for (int i = 0; i < 40; ++i) {
        int o = excl + loc[i];
        offs[t * 40 + i] = o;
        cur[t * 40 + i] = o;
    }
}

__global__ __launch_bounds__(256)
void fill_kernel(const int* __restrict__ rows, int* __restrict__ cur,
                 int* __restrict__ eid, int nnz)
{
    int e = blockIdx.x * 256 + threadIdx.x;
    if (e < nnz) {
        int p = atomicAdd(&cur[rows[e]], 1);
        eid[p] = e;
    }
}

// one wave per user; zero atomics, plain store
__global__ __launch_bounds__(256)
void gather_kernel(const int* __restrict__ offs, const int* __restrict__ eid,
                   const int* __restrict__ cols, const float* __restrict__ vals,
                   const float* __restrict__ A, float* __restrict__ seg, int n_users)
{
    int w = threadIdx.x >> 6;
    int lane = threadIdx.x & 63;
    int u = blockIdx.x * 4 + w;
    if (u >= n_users) return;
    int s0 = offs[u], s1 = offs[u + 1];
    float acc = 0.f;
    for (int i = s0; i < s1; ++i) {
        int e = eid[i];
        float v = vals[e];
        int c = cols[e];
        acc = fmaf(v, A[(long)c * DD + lane], acc);
    }
    seg[(long)u * DD + lane] = acc;
}

// ---------------- stage 3: split-bf16 MFMA flash attention ----------------
// block = (16-user strip) x (news slice of NS); 4 waves partition the slice's chunks.
// QK = Uhi.Bhi + Uhi.Blo + Ulo.Bhi (logit err ~2^-17). PV = Pbf.AThi (err ~2^-9).
// den sums the bf16-ROUNDED p so P-quantization cancels num/den at softmax peaks.
// Block LDS-reduce -> atomicAdd merge into num/den (zero-initialized).
__global__ __launch_bounds__(256)
void attn_kernel(const unsigned short* __restrict__ Uhi, const unsigned short* __restrict__ Ulo,
                 const unsigned short* __restrict__ Bhi, const unsigned short* __restrict__ Blo,
                 const unsigned short* __restrict__ AThi,
                 float* __restrict__ num, float* __restrict__ den)
{
    __shared__ __align__(16) short P[4][16 * PSTRIDE];
    __shared__ float RN[4][16][65];
    __shared__ float RD[4][16];

    int w = threadIdx.x >> 6;
    int lane = threadIdx.x & 63;
    int quad = lane >> 4;
    int l15 = lane & 15;
    int strip = blockIdx.x % 625;
    int slice = blockIdx.x / 625;      // 0..NS-1
    int user0 = strip * 16;

    const short* uh = (const short*)Uhi + ((long)(user0 + l15)) * 64;
    const short* ul = (const short*)Ulo + ((long)(user0 + l15)) * 64;
    short8 uh0 = *(const short8*)(uh + quad * 8);
    short8 uh1 = *(const short8*)(uh + 32 + quad * 8);
    short8 ul0 = *(const short8*)(ul + quad * 8);
    short8 ul1 = *(const short8*)(ul + 32 + quad * 8);

    f32x4 numC[4];
#pragma unroll
    for (int c = 0; c < 4; ++c) numC[c] = (f32x4){0.f, 0.f, 0.f, 0.f};
    float dena[4] = {0.f, 0.f, 0.f, 0.f};
    short* Pw = P[w];

    // chunks ch with ch % NS == slice; the 4 waves take alternating members
    for (int ch = slice + NS * w; ch < NCHUNK; ch += NS * 4) {
        int nb = ch * 32;
        const short* bh = (const short*)Bhi + ((long)(nb + l15)) * 64;
        const short* bl = (const short*)Blo + ((long)(nb + l15)) * 64;
        short8 h00 = *(const short8*)(bh + quad * 8);
        short8 h01 = *(const short8*)(bh + 32 + quad * 8);
        short8 h10 = *(const short8*)(bh + 16 * 64 + quad * 8);
        short8 h11 = *(const short8*)(bh + 16 * 64 + 32 + quad * 8);
        short8 l00 = *(const short8*)(bl + quad * 8);
        short8 l01 = *(const short8*)(bl + 32 + quad * 8);
        short8 l10 = *(const short8*)(bl + 16 * 64 + quad * 8);
        short8 l11 = *(const short8*)(bl + 16 * 64 + 32 + quad * 8);

        f32x4 z = {0.f, 0.f, 0.f, 0.f};
        f32x4 Llo = MFMA16(uh0, h00, z);
        Llo = MFMA16(uh1, h01, Llo);
        Llo = MFMA16(uh0, l00, Llo);
        Llo = MFMA16(uh1, l01, Llo);
        Llo = MFMA16(ul0, h00, Llo);
        Llo = MFMA16(ul1, h01, Llo);
        f32x4 Lhi = MFMA16(uh0, h10, z);
        Lhi = MFMA16(uh1, h11, Lhi);
        Lhi = MFMA16(uh0, l10, Lhi);
        Lhi = MFMA16(uh1, l11, Lhi);
        Lhi = MFMA16(ul0, h10, Lhi);
        Lhi = MFMA16(ul1, h11, Lhi);

        bool vlo = (nb + l15) < 10000;
        bool vhi = (nb + 16 + l15) < 10000;
#pragma unroll
        for (int r = 0; r < 4; ++r) {
            float plo = vlo ? __expf(fminf(Llo[r], 70.f)) : 0.f;
            float phi = vhi ? __expf(fminf(Lhi[r], 70.f)) : 0.f;
            unsigned short qlo = f2bf(plo), qhi = f2bf(phi);
            Pw[(quad * 4 + r) * PSTRIDE + l15] = (short)qlo;
            Pw[(quad * 4 + r) * PSTRIDE + 16 + l15] = (short)qhi;
            dena[r] += bfu2f(qlo) + bfu2f(qhi);
        }
        short8 ap = *(const short8*)(Pw + l15 * PSTRIDE + quad * 8);
#pragma unroll
        for (int c = 0; c < 4; ++c) {
            short8 vh = *(const short8*)((const short*)AThi +
                        ((long)(16 * c + l15)) * ATSTRIDE + nb + quad * 8);
            numC[c] = MFMA16(ap, vh, numC[c]);
        }
    }

#pragma unroll
    for (int r = 0; r < 4; ++r) {
#pragma unroll
        for (int m = 1; m < 16; m <<= 1)
            dena[r] += __shfl_xor(dena[r], m, 64);
    }
    if (l15 == 0) {
#pragma unroll
        for (int r = 0; r < 4; ++r) RD[w][quad * 4 + r] = dena[r];
    }
#pragma unroll
    for (int c = 0; c < 4; ++c)
#pragma unroll
        for (int r = 0; r < 4; ++r)
            RN[w][quad * 4 + r][c * 16 + l15] = numC[c][r];
    __syncthreads();

    int t = threadIdx.x;
#pragma unroll
    for (int i = 0; i < 4; ++i) {
        int idx = i * 256 + t;
        int u = idx >> 6, d = idx & 63;
        float s = RN[0][u][d] + RN[1][u][d] + RN[2][u][d] + RN[3][u][d];
        atomicAdd(&num[(long)(user0 + u) * DD + d], s);
    }
    if (t < 16)
        atomicAdd(&den[user0 + t], RD[0][t] + RD[1][t] + RD[2][t] + RD[3][t]);
}

// ---------------- stage 4: final combine ----------------
__global__ __launch_bounds__(256)
void final_kernel(const float* __restrict__ seg, const float* __restrict__ num,
                  const float* __restrict__ den, float* __restrict__ out, int n_users)
{
    int t = blockIdx.x * 256 + threadIdx.x;
    if (t >= n_users * DD) return;
    int u = t >> 6;
    float s = seg[t];
    float o2 = num[t] / den[u];
    out[t] = fmaf(s, o2, s);
}

extern "C" void kernel_launch(void* const* d_in, const int* in_sizes, int n_in,
                              void* d_out, int out_size, void* d_ws, size_t ws_size,
                              hipStream_t stream)
{
    const float* user_emb = (const float*)d_in[0];
    const float* news_emb = (const float*)d_in[1];
    const float* ent_emb  = (const float*)d_in[2];
    const float* rel_emb  = (const float*)d_in[3];
    const int* news_entities   = (const int*)d_in[4];
    const int* news_relations  = (const int*)d_in[5];
    const int* neigh_entities  = (const int*)d_in[6];
    const int* neigh_relations = (const int*)d_in[7];
    const int* interact_rows   = (const int*)d_in[8];
    const int* interact_cols   = (const int*)d_in[9];
    const float* interact_vals = (const float*)d_in[10];

    const int NU = 10000, NN = 10000, NE = 100000, NNZ = 500000;

    float* out_news = (float*)d_out;
    float* out_ent  = out_news + (long)NN * DD;
    float* out_user = out_ent + (long)NE * DD;

    // Scratch inside the entity-output region (25.6MB; ~16.3MB used).
    // Entity agg runs LAST and overwrites it. No d_ws use.
    float* seg  = out_ent;                           // 640000 f32
    float* num  = seg + 640000;                      // 640000 f32
    float* den  = num + 640000;                      // 10240 f32
    int*   cnt  = (int*)(den + 10240);               // 10240 i32
    int*   offs = cnt + 10240;                       // 10240 i32
    int*   cur  = offs + 10240;                      // 10240 i32
    int*   eid  = cur + 10240;                       // 500000 i32
    unsigned short* Uhi  = (unsigned short*)(eid + 500000);  // 640000 u16 (16B-aligned)
    unsigned short* Ulo  = Uhi + 640000;
    unsigned short* Bhi  = Ulo + 640000;             // 641024 u16
    unsigned short* Blo  = Bhi + 641024;
    unsigned short* AThi = Blo + 641024;             // 641024 u16

    // zero num | den | cnt (contiguous)
    hipMemsetAsync(num, 0, (size_t)(640000 + 10240 + 10240) * sizeof(float), stream);

    // 1) news aggregation -> output 0 (attention K/V source)
    agg_kernel<<<NN / 4, 256, 0, stream>>>(news_emb, ent_emb, rel_emb,
                                           news_entities, news_relations, out_news, NN);
    // 1b) bf16 planes
    split_kernel<<<2500, 256, 0, stream>>>(user_emb, Uhi, Ulo, NU * DD, NU * DD);
    split_kernel<<<2504, 256, 0, stream>>>(out_news, Bhi, Blo, NN * DD, 10016 * DD);
    transpose_kernel<<<(NN + 127) / 128, 256, 0, stream>>>(out_news, AThi);
    // 2) segment-sum via CSR: hist -> scan -> fill -> gather (no fp atomics)
    hist_kernel<<<(NNZ + 255) / 256, 256, 0, stream>>>(interact_rows, cnt, NNZ);
    scan_kernel<<<1, 256, 0, stream>>>(cnt, offs, cur);
    fill_kernel<<<(NNZ + 255) / 256, 256, 0, stream>>>(interact_rows, cur, eid, NNZ);
    gather_kernel<<<(NU + 3) / 4, 256, 0, stream>>>(offs, eid, interact_cols,
                                                    interact_vals, out_news, seg, NU);
    // 3) MFMA attention partials (625 strips x NS slices)
    attn_kernel<<<625 * NS, 256, 0, stream>>>(Uhi, Ulo, Bhi, Blo, AThi, num, den);
    // 4) user output
    final_kernel<<<(NU * DD + 255) / 256, 256, 0, stream>>>(seg, num, den, out_user, NU);
    // 5) entity aggregation LAST — overwrites scratch with output 1
    agg_kernel<<<NE / 4, 256, 0, stream>>>(ent_emb, ent_emb, rel_emb,
                                           neigh_entities, neigh_relations, out_ent, NE);
}

// Round 7
// 630.419 us; speedup vs baseline: 2.9704x; 1.0119x over previous
//
#include <hip/hip_runtime.h>
#include <hip/hip_bf16.h>

// All float tensors are fp32 (verified R1-R5).

#define DD 64
#define KK 20
#define NCHUNK 313        // ceil(10000/32) 32-news chunks
#define NSL 13            // news slices: 625*13 = 8125 waves ~ 8192 device slots
#define ATSTRIDE 10016    // padded news stride of d-major V
#define PSTRIDE 40        // P LDS row stride (shorts)

typedef __attribute__((ext_vector_type(8))) short short8;
typedef __attribute__((ext_vector_type(4))) float f32x4;

__device__ __forceinline__ unsigned short f2bf(float x) {
    union { __hip_bfloat16 h; unsigned short u; } cv;
    cv.h = __float2bfloat16(x);
    return cv.u;
}
__device__ __forceinline__ float bfu2f(unsigned short u) {
    return __uint_as_float(((unsigned)u) << 16);
}
#define MFMA16(a, b, c) __builtin_amdgcn_mfma_f32_16x16x32_bf16((a), (b), (c), 0, 0, 0)

// ---------------- stage 1: news / entity aggregation (fp32) ----------------
__global__ __launch_bounds__(256)
void agg_kernel(const float* __restrict__ head_emb, const float* __restrict__ ent_emb,
                const float* __restrict__ rel_emb,
                const int* __restrict__ ent_idx, const int* __restrict__ rel_idx,
                float* __restrict__ outp, int N)
{
    int wave = threadIdx.x >> 6;
    int lane = threadIdx.x & 63;
    int n = blockIdx.x * 4 + wave;
    if (n >= N) return;

    float head = head_emb[(long)n * DD + lane];

    float tail[KK], trp[KK];
    float s2 = 0.f;
#pragma unroll
    for (int k = 0; k < KK; ++k) {
        int e = ent_idx[n * KK + k];
        int r = rel_idx[n * KK + k];
        float rv = rel_emb[(long)r * DD + lane];
        float tv = ent_emb[(long)e * DD + lane];
        tail[k] = tv;
        trp[k] = tv * rv;
        s2 = fmaf(rv, rv, s2);
    }
    float hn = fabsf(head) * sqrtf(s2);   // ref's axis=1 norm

    float att[KK];
#pragma unroll
    for (int k = 0; k < KK; ++k) {
        float v = trp[k] * hn;
#pragma unroll
        for (int off = 32; off > 0; off >>= 1)
            v += __shfl_xor(v, off, 64);
        att[k] = v * v;
    }
    float mx = att[0];
#pragma unroll
    for (int k = 1; k < KK; ++k) mx = fmaxf(mx, att[k]);
    float den = 0.f;
#pragma unroll
    for (int k = 0; k < KK; ++k) { att[k] = __expf(att[k] - mx); den += att[k]; }
    float inv = 1.f / den;
    float o = 0.f;
#pragma unroll
    for (int k = 0; k < KK; ++k) o = fmaf(att[k], tail[k], o);
    outp[(long)n * DD + lane] = o * inv;
}

// ---------------- stage 1b: split fp32 -> bf16 hi + lo (row-major) ----------------
__global__ __launch_bounds__(256)
void split_kernel(const float* __restrict__ src, unsigned short* __restrict__ hi,
                  unsigned short* __restrict__ lo, int n_src, int n_total)
{
    int t = blockIdx.x * 256 + threadIdx.x;
    if (t >= n_total) return;
    float v = (t < n_src) ? src[t] : 0.f;
    unsigned short h = f2bf(v);
    hi[t] = h;
    lo[t] = f2bf(v - bfu2f(h));
}

// ---------------- stage 1c: transpose newsagg [10000][64] -> AThi bf16 [64][10016] ----------------
__global__ __launch_bounds__(256)
void transpose_kernel(const float* __restrict__ src, unsigned short* __restrict__ AThi)
{
    __shared__ float T[128][65];
    int t = threadIdx.x;
    int nb = blockIdx.x * 128;
    const float4* s4 = (const float4*)src;
#pragma unroll
    for (int i = 0; i < 8; ++i) {
        int f = i * 256 + t;
        int row = f >> 4;
        int c4 = f & 15;
        int gr = nb + row;
        float4 v = make_float4(0.f, 0.f, 0.f, 0.f);
        if (gr < 10000) v = s4[(long)gr * 16 + c4];
        T[row][c4 * 4 + 0] = v.x;
        T[row][c4 * 4 + 1] = v.y;
        T[row][c4 * 4 + 2] = v.z;
        T[row][c4 * 4 + 3] = v.w;
    }
    __syncthreads();
    int d = t >> 2;
    int seg = t & 3;
#pragma unroll
    for (int g = 0; g < 8; ++g) {
        int nl = seg * 32 + g * 4;
        int n = nb + nl;
        if (n + 3 < ATSTRIDE) {
            ushort4 oh;
            oh.x = f2bf(T[nl + 0][d]);
            oh.y = f2bf(T[nl + 1][d]);
            oh.z = f2bf(T[nl + 2][d]);
            oh.w = f2bf(T[nl + 3][d]);
            *(ushort4*)(AThi + (long)d * ATSTRIDE + n) = oh;
        }
    }
}

// ---------------- stage 2: segment-sum via CSR (hist/scan/fill/gather) ----------------
__global__ __launch_bounds__(256)
void hist_kernel(const int* __restrict__ rows, int* __restrict__ cnt, int nnz)
{
    int e = blockIdx.x * 256 + threadIdx.x;
    if (e < nnz) atomicAdd(&cnt[rows[e]], 1);
}

// single block; 256 threads x 40 rows = 10240 >= 10001 needed
__global__ __launch_bounds__(256)
void scan_kernel(const int* __restrict__ cnt, int* __restrict__ offs, int* __restrict__ cur)
{
    __shared__ int ssum[256];
    int t = threadIdx.x;
    int loc[40];
    int s = 0;
#pragma unroll
    for (int i = 0; i < 40; ++i) { loc[i] = s; s += cnt[t * 40 + i]; }
    ssum[t] = s;
    __syncthreads();
    int val = s;
    for (int off = 1; off < 256; off <<= 1) {
        int v = (t >= off) ? ssum[t - off] : 0;
        __syncthreads();
        val += v;
        ssum[t] = val;
        __syncthreads();
    }
    int excl = val - s;
#pragma unroll
    for (int i = 0; i < 40; ++i) {
        int o = excl + loc[i];
        offs[t * 40 + i] = o;
        cur[t * 40 + i] = o;
    }
}

__global__ __launch_bounds__(256)
void fill_kernel(const int* __restrict__ rows, int* __restrict__ cur,
                 int* __restrict__ eid, int nnz)
{
    int e = blockIdx.x * 256 + threadIdx.x;
    if (e < nnz) {
        int p = atomicAdd(&cur[rows[e]], 1);
        eid[p] = e;
    }
}

// one wave per user; zero atomics, plain store
__global__ __launch_bounds__(256)
void gather_kernel(const int* __restrict__ offs, const int* __restrict__ eid,
                   const int* __restrict__ cols, const float* __restrict__ vals,
                   const float* __restrict__ A, float* __restrict__ seg, int n_users)
{
    int w = threadIdx.x >> 6;
    int lane = threadIdx.x & 63;
    int u = blockIdx.x * 4 + w;
    if (u >= n_users) return;
    int s0 = offs[u], s1 = offs[u + 1];
    float acc = 0.f;
    for (int i = s0; i < s1; ++i) {
        int e = eid[i];
        float v = vals[e];
        int c = cols[e];
        acc = fmaf(v, A[(long)c * DD + lane], acc);
    }
    seg[(long)u * DD + lane] = acc;
}

// ---------------- stage 3: split-bf16 MFMA flash attention ----------------
// ONE WAVE = (16-user strip) x (1-of-13 news slice). No cross-wave coupling:
// LDS is only the wave-private P buffer (5 KB/block) -> 8 blocks/CU residency.
// QK = Uhi.Bhi + Uhi.Blo + Ulo.Bhi as TWO independent MFMA chains (halved dep
// depth). den sums bf16-ROUNDED p so P-quantization cancels num/den at peaks.
// Merge across slices via atomicAdd into zero-initialized num/den.
__global__ __launch_bounds__(256)
void attn_kernel(const unsigned short* __restrict__ Uhi, const unsigned short* __restrict__ Ulo,
                 const unsigned short* __restrict__ Bhi, const unsigned short* __restrict__ Blo,
                 const unsigned short* __restrict__ AThi,
                 float* __restrict__ num, float* __restrict__ den)
{
    __shared__ __align__(16) short P[4][16 * PSTRIDE];

    int w = threadIdx.x >> 6;
    int lane = threadIdx.x & 63;
    int quad = lane >> 4;
    int l15 = lane & 15;
    int wid = blockIdx.x * 4 + w;
    if (wid >= 625 * NSL) return;
    int strip = wid % 625;
    int slice = wid / 625;             // 0..NSL-1
    int user0 = strip * 16;

    const short* uh = (const short*)Uhi + ((long)(user0 + l15)) * 64;
    const short* ul = (const short*)Ulo + ((long)(user0 + l15)) * 64;
    short8 uh0 = *(const short8*)(uh + quad * 8);
    short8 uh1 = *(const short8*)(uh + 32 + quad * 8);
    short8 ul0 = *(const short8*)(ul + quad * 8);
    short8 ul1 = *(const short8*)(ul + 32 + quad * 8);

    f32x4 numC[4];
#pragma unroll
    for (int c = 0; c < 4; ++c) numC[c] = (f32x4){0.f, 0.f, 0.f, 0.f};
    float dena[4] = {0.f, 0.f, 0.f, 0.f};
    short* Pw = P[w];

    for (int ch = slice; ch < NCHUNK; ch += NSL) {
        int nb = ch * 32;
        const short* bh = (const short*)Bhi + ((long)(nb + l15)) * 64;
        const short* bl = (const short*)Blo + ((long)(nb + l15)) * 64;
        short8 h00 = *(const short8*)(bh + quad * 8);
        short8 h01 = *(const short8*)(bh + 32 + quad * 8);
        short8 h10 = *(const short8*)(bh + 16 * 64 + quad * 8);
        short8 h11 = *(const short8*)(bh + 16 * 64 + 32 + quad * 8);
        short8 l00 = *(const short8*)(bl + quad * 8);
        short8 l01 = *(const short8*)(bl + 32 + quad * 8);
        short8 l10 = *(const short8*)(bl + 16 * 64 + quad * 8);
        short8 l11 = *(const short8*)(bl + 16 * 64 + 32 + quad * 8);

        f32x4 z = {0.f, 0.f, 0.f, 0.f};
        // two independent accumulator chains per tile
        f32x4 La = MFMA16(uh0, h00, z);
        f32x4 Lb = MFMA16(uh1, h01, z);
        La = MFMA16(uh0, l00, La);
        Lb = MFMA16(uh1, l01, Lb);
        La = MFMA16(ul0, h00, La);
        Lb = MFMA16(ul1, h01, Lb);
        f32x4 Ha = MFMA16(uh0, h10, z);
        f32x4 Hb = MFMA16(uh1, h11, z);
        Ha = MFMA16(uh0, l10, Ha);
        Hb = MFMA16(uh1, l11, Hb);
        Ha = MFMA16(ul0, h10, Ha);
        Hb = MFMA16(ul1, h11, Hb);
        f32x4 Llo = La + Lb;
        f32x4 Lhi = Ha + Hb;

        bool vlo = (nb + l15) < 10000;
        bool vhi = (nb + 16 + l15) < 10000;
#pragma unroll
        for (int r = 0; r < 4; ++r) {
            float plo = vlo ? __expf(fminf(Llo[r], 70.f)) : 0.f;
            float phi = vhi ? __expf(fminf(Lhi[r], 70.f)) : 0.f;
            unsigned short qlo = f2bf(plo), qhi = f2bf(phi);
            Pw[(quad * 4 + r) * PSTRIDE + l15] = (short)qlo;
            Pw[(quad * 4 + r) * PSTRIDE + 16 + l15] = (short)qhi;
            dena[r] += bfu2f(qlo) + bfu2f(qhi);
        }
        short8 ap = *(const short8*)(Pw + l15 * PSTRIDE + quad * 8);
#pragma unroll
        for (int c = 0; c < 4; ++c) {
            short8 vh = *(const short8*)((const short*)AThi +
                        ((long)(16 * c + l15)) * ATSTRIDE + nb + quad * 8);
            numC[c] = MFMA16(ap, vh, numC[c]);
        }
    }

    // den: butterfly over the 16 news-lanes (l15) within each quad
#pragma unroll
    for (int r = 0; r < 4; ++r) {
#pragma unroll
        for (int m = 1; m < 16; m <<= 1)
            dena[r] += __shfl_xor(dena[r], m, 64);
    }
    if (l15 == 0) {
#pragma unroll
        for (int r = 0; r < 4; ++r)
            atomicAdd(&den[user0 + quad * 4 + r], dena[r]);
    }
#pragma unroll
    for (int c = 0; c < 4; ++c)
#pragma unroll
        for (int r = 0; r < 4; ++r)
            atomicAdd(&num[(long)(user0 + quad * 4 + r) * DD + c * 16 + l15], numC[c][r]);
}

// ---------------- stage 4: final combine ----------------
__global__ __launch_bounds__(256)
void final_kernel(const float* __restrict__ seg, const float* __restrict__ num,
                  const float* __restrict__ den, float* __restrict__ out, int n_users)
{
    int t = blockIdx.x * 256 + threadIdx.x;
    if (t >= n_users * DD) return;
    int u = t >> 6;
    float s = seg[t];
    float o2 = num[t] / den[u];
    out[t] = fmaf(s, o2, s);
}

extern "C" void kernel_launch(void* const* d_in, const int* in_sizes, int n_in,
                              void* d_out, int out_size, void* d_ws, size_t ws_size,
                              hipStream_t stream)
{
    const float* user_emb = (const float*)d_in[0];
    const float* news_emb = (const float*)d_in[1];
    const float* ent_emb  = (const float*)d_in[2];
    const float* rel_emb  = (const float*)d_in[3];
    const int* news_entities   = (const int*)d_in[4];
    const int* news_relations  = (const int*)d_in[5];
    const int* neigh_entities  = (const int*)d_in[6];
    const int* neigh_relations = (const int*)d_in[7];
    const int* interact_rows   = (const int*)d_in[8];
    const int* interact_cols   = (const int*)d_in[9];
    const float* interact_vals = (const float*)d_in[10];

    const int NU = 10000, NN = 10000, NE = 100000, NNZ = 500000;

    float* out_news = (float*)d_out;
    float* out_ent  = out_news + (long)NN * DD;
    float* out_user = out_ent + (long)NE * DD;

    // Scratch inside the entity-output region (25.6MB; ~16.3MB used).
    // Entity agg runs LAST and overwrites it. No d_ws use.
    float* seg  = out_ent;                           // 640000 f32
    float* num  = seg + 640000;                      // 640000 f32
    float* den  = num + 640000;                      // 10240 f32
    int*   cnt  = (int*)(den + 10240);               // 10240 i32
    int*   offs = cnt + 10240;                       // 10240 i32
    int*   cur  = offs + 10240;                      // 10240 i32
    int*   eid  = cur + 10240;                       // 500000 i32
    unsigned short* Uhi  = (unsigned short*)(eid + 500000);  // 640000 u16 (16B-aligned)
    unsigned short* Ulo  = Uhi + 640000;
    unsigned short* Bhi  = Ulo + 640000;             // 641024 u16
    unsigned short* Blo  = Bhi + 641024;
    unsigned short* AThi = Blo + 641024;             // 641024 u16

    // zero num | den | cnt (contiguous)
    hipMemsetAsync(num, 0, (size_t)(640000 + 10240 + 10240) * sizeof(float), stream);

    // 1) news aggregation -> output 0 (attention K/V source)
    agg_kernel<<<NN / 4, 256, 0, stream>>>(news_emb, ent_emb, rel_emb,
                                           news_entities, news_relations, out_news, NN);
    // 1b) bf16 planes
    split_kernel<<<2500, 256, 0, stream>>>(user_emb, Uhi, Ulo, NU * DD, NU * DD);
    split_kernel<<<2504, 256, 0, stream>>>(out_news, Bhi, Blo, NN * DD, 10016 * DD);
    transpose_kernel<<<(NN + 127) / 128, 256, 0, stream>>>(out_news, AThi);
    // 2) segment-sum via CSR: hist -> scan -> fill -> gather (no fp atomics)
    hist_kernel<<<(NNZ + 255) / 256, 256, 0, stream>>>(interact_rows, cnt, NNZ);
    scan_kernel<<<1, 256, 0, stream>>>(cnt, offs, cur);
    fill_kernel<<<(NNZ + 255) / 256, 256, 0, stream>>>(interact_rows, cur, eid, NNZ);
    gather_kernel<<<(NU + 3) / 4, 256, 0, stream>>>(offs, eid, interact_cols,
                                                    interact_vals, out_news, seg, NU);
    // 3) MFMA attention partials: 8125 independent waves (625 strips x 13 slices)
    attn_kernel<<<(625 * NSL + 3) / 4, 256, 0, stream>>>(Uhi, Ulo, Bhi, Blo, AThi, num, den);
    // 4) user output
    final_kernel<<<(NU * DD + 255) / 256, 256, 0, stream>>>(seg, num, den, out_user, NU);
    // 5) entity aggregation LAST — overwrites scratch with output 1
    agg_kernel<<<NE / 4, 256, 0, stream>>>(ent_emb, ent_emb, rel_emb,
                                           neigh_entities, neigh_relations, out_ent, NE);
}

// Round 8
// 505.030 us; speedup vs baseline: 3.7078x; 1.2483x over previous
//
#include <hip/hip_runtime.h>
#include <hip/hip_bf16.h>

// All float tensors are fp32 (verified R1-R5).

#define DD 64
#define KK 20
#define NCHUNK 313        // ceil(10000/32) 32-news chunks
#define NSL 13            // news slices: 313 strips x 13 = 4069 waves (~1 round)
#define NSTRIP 313        // 32-user strips (10016 padded users)
#define ATSTRIDE 10016    // padded news stride of d-major V
#define PSTRIDE 40        // P LDS row stride (shorts)

typedef __attribute__((ext_vector_type(8))) short short8;
typedef __attribute__((ext_vector_type(4))) float f32x4;

__device__ __forceinline__ unsigned short f2bf(float x) {
    union { __hip_bfloat16 h; unsigned short u; } cv;
    cv.h = __float2bfloat16(x);
    return cv.u;
}
__device__ __forceinline__ float bfu2f(unsigned short u) {
    return __uint_as_float(((unsigned)u) << 16);
}
#define MFMA16(a, b, c) __builtin_amdgcn_mfma_f32_16x16x32_bf16((a), (b), (c), 0, 0, 0)

// ---------------- stage 1: news / entity aggregation (fp32) ----------------
__global__ __launch_bounds__(256)
void agg_kernel(const float* __restrict__ head_emb, const float* __restrict__ ent_emb,
                const float* __restrict__ rel_emb,
                const int* __restrict__ ent_idx, const int* __restrict__ rel_idx,
                float* __restrict__ outp, int N)
{
    int wave = threadIdx.x >> 6;
    int lane = threadIdx.x & 63;
    int n = blockIdx.x * 4 + wave;
    if (n >= N) return;

    float head = head_emb[(long)n * DD + lane];

    float tail[KK], trp[KK];
    float s2 = 0.f;
#pragma unroll
    for (int k = 0; k < KK; ++k) {
        int e = ent_idx[n * KK + k];
        int r = rel_idx[n * KK + k];
        float rv = rel_emb[(long)r * DD + lane];
        float tv = ent_emb[(long)e * DD + lane];
        tail[k] = tv;
        trp[k] = tv * rv;
        s2 = fmaf(rv, rv, s2);
    }
    float hn = fabsf(head) * sqrtf(s2);   // ref's axis=1 norm

    float att[KK];
#pragma unroll
    for (int k = 0; k < KK; ++k) {
        float v = trp[k] * hn;
#pragma unroll
        for (int off = 32; off > 0; off >>= 1)
            v += __shfl_xor(v, off, 64);
        att[k] = v * v;
    }
    float mx = att[0];
#pragma unroll
    for (int k = 1; k < KK; ++k) mx = fmaxf(mx, att[k]);
    float den = 0.f;
#pragma unroll
    for (int k = 0; k < KK; ++k) { att[k] = __expf(att[k] - mx); den += att[k]; }
    float inv = 1.f / den;
    float o = 0.f;
#pragma unroll
    for (int k = 0; k < KK; ++k) o = fmaf(att[k], tail[k], o);
    outp[(long)n * DD + lane] = o * inv;
}

// ---------------- stage 1b: fp32 -> bf16 (zero-padded rows) ----------------
__global__ __launch_bounds__(256)
void cvt_kernel(const float* __restrict__ src, unsigned short* __restrict__ dst,
                int n_src, int n_total)
{
    int t = blockIdx.x * 256 + threadIdx.x;
    if (t >= n_total) return;
    float v = (t < n_src) ? src[t] : 0.f;
    dst[t] = f2bf(v);
}

// ---------------- stage 1c: transpose newsagg [10000][64] -> AT bf16 [64][10016] ----------------
__global__ __launch_bounds__(256)
void transpose_kernel(const float* __restrict__ src, unsigned short* __restrict__ AT)
{
    __shared__ float T[128][65];
    int t = threadIdx.x;
    int nb = blockIdx.x * 128;
    const float4* s4 = (const float4*)src;
#pragma unroll
    for (int i = 0; i < 8; ++i) {
        int f = i * 256 + t;
        int row = f >> 4;
        int c4 = f & 15;
        int gr = nb + row;
        float4 v = make_float4(0.f, 0.f, 0.f, 0.f);
        if (gr < 10000) v = s4[(long)gr * 16 + c4];
        T[row][c4 * 4 + 0] = v.x;
        T[row][c4 * 4 + 1] = v.y;
        T[row][c4 * 4 + 2] = v.z;
        T[row][c4 * 4 + 3] = v.w;
    }
    __syncthreads();
    int d = t >> 2;
    int seg = t & 3;
#pragma unroll
    for (int g = 0; g < 8; ++g) {
        int nl = seg * 32 + g * 4;
        int n = nb + nl;
        if (n + 3 < ATSTRIDE) {
            ushort4 oh;
            oh.x = f2bf(T[nl + 0][d]);
            oh.y = f2bf(T[nl + 1][d]);
            oh.z = f2bf(T[nl + 2][d]);
            oh.w = f2bf(T[nl + 3][d]);
            *(ushort4*)(AT + (long)d * ATSTRIDE + n) = oh;
        }
    }
}

// ---------------- stage 2: segment-sum via CSR (hist/scan/fill/gather) ----------------
__global__ __launch_bounds__(256)
void hist_kernel(const int* __restrict__ rows, int* __restrict__ cnt, int nnz)
{
    int e = blockIdx.x * 256 + threadIdx.x;
    if (e < nnz) atomicAdd(&cnt[rows[e]], 1);
}

// single block; 256 threads x 40 rows = 10240 >= 10001 needed
__global__ __launch_bounds__(256)
void scan_kernel(const int* __restrict__ cnt, int* __restrict__ offs, int* __restrict__ cur)
{
    __shared__ int ssum[256];
    int t = threadIdx.x;
    int loc[40];
    int s = 0;
#pragma unroll
    for (int i = 0; i < 40; ++i) { loc[i] = s; s += cnt[t * 40 + i]; }
    ssum[t] = s;
    __syncthreads();
    int val = s;
    for (int off = 1; off < 256; off <<= 1) {
        int v = (t >= off) ? ssum[t - off] : 0;
        __syncthreads();
        val += v;
        ssum[t] = val;
        __syncthreads();
    }
    int excl = val - s;
#pragma unroll
    for (int i = 0; i < 40; ++i) {
        int o = excl + loc[i];
        offs[t * 40 + i] = o;
        cur[t * 40 + i] = o;
    }
}

__global__ __launch_bounds__(256)
void fill_kernel(const int* __restrict__ rows, int* __restrict__ cur,
                 int* __restrict__ eid, int nnz)
{
    int e = blockIdx.x * 256 + threadIdx.x;
    if (e < nnz) {
        int p = atomicAdd(&cur[rows[e]], 1);
        eid[p] = e;
    }
}

// one wave per user; zero atomics, plain store
__global__ __launch_bounds__(256)
void gather_kernel(const int* __restrict__ offs, const int* __restrict__ eid,
                   const int* __restrict__ cols, const float* __restrict__ vals,
                   const float* __restrict__ A, float* __restrict__ seg, int n_users)
{
    int w = threadIdx.x >> 6;
    int lane = threadIdx.x & 63;
    int u = blockIdx.x * 4 + w;
    if (u >= n_users) return;
    int s0 = offs[u], s1 = offs[u + 1];
    float acc = 0.f;
    for (int i = s0; i < s1; ++i) {
        int e = eid[i];
        float v = vals[e];
        int c = cols[e];
        acc = fmaf(v, A[(long)c * DD + lane], acc);
    }
    seg[(long)u * DD + lane] = acc;
}

// ---------------- stage 3: bf16 MFMA flash attention, 32 users/wave ----------------
// ONE WAVE = (32-user strip = two 16-row MFMA tiles) x (1-of-13 news slice).
// B/AT fragment loads are shared across both strips -> VMEM traffic / 3 vs R7
// (8 loads per 32-news chunk for 32 users). QK is plain bf16 (logit quant err
// ~0.005 abs); den sums the bf16-ROUNDED p so P-quantization cancels num/den.
// Merge across slices via atomicAdd into zero-initialized num/den (10016 rows).
__global__ __launch_bounds__(256)
void attn_kernel(const unsigned short* __restrict__ Ubf,
                 const unsigned short* __restrict__ Bbf,
                 const unsigned short* __restrict__ ATbf,
                 float* __restrict__ num, float* __restrict__ den)
{
    __shared__ __align__(16) short P[4][2][16 * PSTRIDE];

    int w = threadIdx.x >> 6;
    int lane = threadIdx.x & 63;
    int quad = lane >> 4;
    int l15 = lane & 15;
    int wid = blockIdx.x * 4 + w;
    if (wid >= NSTRIP * NSL) return;
    int strip = wid % NSTRIP;
    int slice = wid / NSTRIP;          // 0..NSL-1
    int user0 = strip * 32;

    // A-frags for the two 16-user tiles (rows user0.. and user0+16..)
    const short* u0 = (const short*)Ubf + ((long)(user0 + l15)) * 64;
    const short* u1 = u0 + 16 * 64;
    short8 ua00 = *(const short8*)(u0 + quad * 8);        // tile0, k 0..31
    short8 ua01 = *(const short8*)(u0 + 32 + quad * 8);   // tile0, k 32..63
    short8 ua10 = *(const short8*)(u1 + quad * 8);
    short8 ua11 = *(const short8*)(u1 + 32 + quad * 8);

    f32x4 numC0[4], numC1[4];
#pragma unroll
    for (int c = 0; c < 4; ++c) {
        numC0[c] = (f32x4){0.f, 0.f, 0.f, 0.f};
        numC1[c] = (f32x4){0.f, 0.f, 0.f, 0.f};
    }
    float dena0[4] = {0.f, 0.f, 0.f, 0.f};
    float dena1[4] = {0.f, 0.f, 0.f, 0.f};
    short* P0 = P[w][0];
    short* P1 = P[w][1];

    for (int ch = slice; ch < NCHUNK; ch += NSL) {
        int nb = ch * 32;
        const short* bh = (const short*)Bbf + ((long)(nb + l15)) * 64;
        short8 b00 = *(const short8*)(bh + quad * 8);             // news lo, k0
        short8 b01 = *(const short8*)(bh + 32 + quad * 8);        // news lo, k1
        short8 b10 = *(const short8*)(bh + 16 * 64 + quad * 8);   // news hi, k0
        short8 b11 = *(const short8*)(bh + 16 * 64 + 32 + quad * 8);

        f32x4 z = {0.f, 0.f, 0.f, 0.f};
        f32x4 L0lo = MFMA16(ua00, b00, z);  L0lo = MFMA16(ua01, b01, L0lo);
        f32x4 L0hi = MFMA16(ua00, b10, z);  L0hi = MFMA16(ua01, b11, L0hi);
        f32x4 L1lo = MFMA16(ua10, b00, z);  L1lo = MFMA16(ua11, b01, L1lo);
        f32x4 L1hi = MFMA16(ua10, b10, z);  L1hi = MFMA16(ua11, b11, L1hi);

        bool vlo = (nb + l15) < 10000;
        bool vhi = (nb + 16 + l15) < 10000;
#pragma unroll
        for (int r = 0; r < 4; ++r) {
            float p0l = vlo ? __expf(fminf(L0lo[r], 70.f)) : 0.f;
            float p0h = vhi ? __expf(fminf(L0hi[r], 70.f)) : 0.f;
            float p1l = vlo ? __expf(fminf(L1lo[r], 70.f)) : 0.f;
            float p1h = vhi ? __expf(fminf(L1hi[r], 70.f)) : 0.f;
            unsigned short q0l = f2bf(p0l), q0h = f2bf(p0h);
            unsigned short q1l = f2bf(p1l), q1h = f2bf(p1h);
            // C-layout -> LDS: row(user_local)=quad*4+r, col(news_local)=l15 (+16)
            P0[(quad * 4 + r) * PSTRIDE + l15]      = (short)q0l;
            P0[(quad * 4 + r) * PSTRIDE + 16 + l15] = (short)q0h;
            P1[(quad * 4 + r) * PSTRIDE + l15]      = (short)q1l;
            P1[(quad * 4 + r) * PSTRIDE + 16 + l15] = (short)q1h;
            dena0[r] += bfu2f(q0l) + bfu2f(q0h);
            dena1[r] += bfu2f(q1l) + bfu2f(q1h);
        }
        // PV: P A-frags from LDS (m120 layout swap), shared V B-frags from AT
        short8 ap0 = *(const short8*)(P0 + l15 * PSTRIDE + quad * 8);
        short8 ap1 = *(const short8*)(P1 + l15 * PSTRIDE + quad * 8);
#pragma unroll
        for (int c = 0; c < 4; ++c) {
            short8 vh = *(const short8*)((const short*)ATbf +
                        ((long)(16 * c + l15)) * ATSTRIDE + nb + quad * 8);
            numC0[c] = MFMA16(ap0, vh, numC0[c]);
            numC1[c] = MFMA16(ap1, vh, numC1[c]);
        }
    }

    // den: butterfly over the 16 news-lanes (l15) within each quad
#pragma unroll
    for (int r = 0; r < 4; ++r) {
#pragma unroll
        for (int m = 1; m < 16; m <<= 1) {
            dena0[r] += __shfl_xor(dena0[r], m, 64);
            dena1[r] += __shfl_xor(dena1[r], m, 64);
        }
    }
    if (l15 == 0) {
#pragma unroll
        for (int r = 0; r < 4; ++r) {
            atomicAdd(&den[user0 + quad * 4 + r], dena0[r]);
            atomicAdd(&den[user0 + 16 + quad * 4 + r], dena1[r]);
        }
    }
#pragma unroll
    for (int c = 0; c < 4; ++c)
#pragma unroll
        for (int r = 0; r < 4; ++r) {
            atomicAdd(&num[(long)(user0 + quad * 4 + r) * DD + c * 16 + l15], numC0[c][r]);
            atomicAdd(&num[(long)(user0 + 16 + quad * 4 + r) * DD + c * 16 + l15], numC1[c][r]);
        }
}

// ---------------- stage 4: final combine ----------------
__global__ __launch_bounds__(256)
void final_kernel(const float* __restrict__ seg, const float* __restrict__ num,
                  const float* __restrict__ den, float* __restrict__ out, int n_users)
{
    int t = blockIdx.x * 256 + threadIdx.x;
    if (t >= n_users * DD) return;
    int u = t >> 6;
    float s = seg[t];
    float o2 = num[t] / den[u];
    out[t] = fmaf(s, o2, s);
}

extern "C" void kernel_launch(void* const* d_in, const int* in_sizes, int n_in,
                              void* d_out, int out_size, void* d_ws, size_t ws_size,
                              hipStream_t stream)
{
    const float* user_emb = (const float*)d_in[0];
    const float* news_emb = (const float*)d_in[1];
    const float* ent_emb  = (const float*)d_in[2];
    const float* rel_emb  = (const float*)d_in[3];
    const int* news_entities   = (const int*)d_in[4];
    const int* news_relations  = (const int*)d_in[5];
    const int* neigh_entities  = (const int*)d_in[6];
    const int* neigh_relations = (const int*)d_in[7];
    const int* interact_rows   = (const int*)d_in[8];
    const int* interact_cols   = (const int*)d_in[9];
    const float* interact_vals = (const float*)d_in[10];

    const int NU = 10000, NN = 10000, NE = 100000, NNZ = 500000;

    float* out_news = (float*)d_out;
    float* out_ent  = out_news + (long)NN * DD;
    float* out_user = out_ent + (long)NE * DD;

    // Scratch inside the entity-output region (25.6MB; ~11.2MB used).
    // Entity agg runs LAST and overwrites it. No d_ws use.
    float* seg  = out_ent;                           // 640000 f32
    float* num  = seg + 640000;                      // 641024 f32 (10016 users)
    float* den  = num + 641024;                      // 10240 f32
    int*   cnt  = (int*)(den + 10240);               // 10240 i32
    int*   offs = cnt + 10240;                       // 10240 i32
    int*   cur  = offs + 10240;                      // 10240 i32
    int*   eid  = cur + 10240;                       // 500000 i32
    unsigned short* Ubf  = (unsigned short*)(eid + 500000);  // 641024 u16 (16B-aligned)
    unsigned short* Bbf  = Ubf + 641024;             // 641024 u16
    unsigned short* ATbf = Bbf + 641024;             // 641024 u16

    // zero num | den | cnt (contiguous)
    hipMemsetAsync(num, 0, (size_t)(641024 + 10240 + 10240) * sizeof(float), stream);

    // 1) news aggregation -> output 0 (attention K/V source)
    agg_kernel<<<NN / 4, 256, 0, stream>>>(news_emb, ent_emb, rel_emb,
                                           news_entities, news_relations, out_news, NN);
    // 1b) bf16 conversions (zero-padded to 10016 rows)
    cvt_kernel<<<2504, 256, 0, stream>>>(user_emb, Ubf, NU * DD, 10016 * DD);
    cvt_kernel<<<2504, 256, 0, stream>>>(out_news, Bbf, NN * DD, 10016 * DD);
    transpose_kernel<<<(NN + 127) / 128, 256, 0, stream>>>(out_news, ATbf);
    // 2) segment-sum via CSR: hist -> scan -> fill -> gather (no fp atomics)
    hist_kernel<<<(NNZ + 255) / 256, 256, 0, stream>>>(interact_rows, cnt, NNZ);
    scan_kernel<<<1, 256, 0, stream>>>(cnt, offs, cur);
    fill_kernel<<<(NNZ + 255) / 256, 256, 0, stream>>>(interact_rows, cur, eid, NNZ);
    gather_kernel<<<(NU + 3) / 4, 256, 0, stream>>>(offs, eid, interact_cols,
                                                    interact_vals, out_news, seg, NU);
    // 3) MFMA attention partials: 4069 independent waves (313 strips x 13 slices)
    attn_kernel<<<(NSTRIP * NSL + 3) / 4, 256, 0, stream>>>(Ubf, Bbf, ATbf, num, den);
    // 4) user output
    final_kernel<<<(NU * DD + 255) / 256, 256, 0, stream>>>(seg, num, den, out_user, NU);
    // 5) entity aggregation LAST — overwrites scratch with output 1
    agg_kernel<<<NE / 4, 256, 0, stream>>>(ent_emb, ent_emb, rel_emb,
                                           neigh_entities, neigh_relations, out_ent, NE);
}

// Round 9
// 485.429 us; speedup vs baseline: 3.8576x; 1.0404x over previous
//
#include <hip/hip_runtime.h>
#include <hip/hip_bf16.h>

// All float tensors are fp32 (verified R1-R5).

#define DD 64
#define KK 20
#define NCHUNK 313        // ceil(10000/32) 32-news chunks
#define NSL 20            // news slices: 157 strips x 20 = 3140 waves (~3/SIMD round)
#define NSTRIP 157        // 64-user strips (10048 padded users)
#define NUPAD 10048
#define ATSTRIDE 10016    // padded news stride of d-major V
#define PSTRIDE 40        // P LDS row stride (shorts)

typedef __attribute__((ext_vector_type(8))) short short8;
typedef __attribute__((ext_vector_type(4))) float f32x4;

__device__ __forceinline__ unsigned short f2bf(float x) {
    union { __hip_bfloat16 h; unsigned short u; } cv;
    cv.h = __float2bfloat16(x);
    return cv.u;
}
__device__ __forceinline__ float bfu2f(unsigned short u) {
    return __uint_as_float(((unsigned)u) << 16);
}
#define MFMA16(a, b, c) __builtin_amdgcn_mfma_f32_16x16x32_bf16((a), (b), (c), 0, 0, 0)

// ---------------- stage 1: news / entity aggregation (fp32) ----------------
// TWO rows per wave: lanes 0-31 = row n0, lanes 32-63 = row n0+1; each lane
// holds d = {2l, 2l+1} as float2. The 5-step butterfly (within 32-lane halves)
// and the softmax are shared by both rows -> ~40% VALU cut vs 1 row/wave.
__global__ __launch_bounds__(256)
void agg_kernel(const float* __restrict__ head_emb, const float* __restrict__ ent_emb,
                const float* __restrict__ rel_emb,
                const int* __restrict__ ent_idx, const int* __restrict__ rel_idx,
                float* __restrict__ outp, int N)
{
    int w = threadIdx.x >> 6;
    int lane = threadIdx.x & 63;
    int half = lane >> 5;              // which row of the pair
    int l = lane & 31;                 // d pair: d = 2l, 2l+1
    int n0 = blockIdx.x * 8 + w * 2;   // wave-uniform
    if (n0 >= N) return;               // N % 8 == 0 in all our calls

    float2 head = *(const float2*)(head_emb + (long)(n0 + half) * DD + 2 * l);

    float2 tail[KK], trp[KK];
    float2 s2 = make_float2(0.f, 0.f);
#pragma unroll
    for (int k = 0; k < KK; ++k) {
        int ei0 = ent_idx[n0 * KK + k];            // scalar loads (uniform)
        int ei1 = ent_idx[(n0 + 1) * KK + k];
        int ri0 = rel_idx[n0 * KK + k];
        int ri1 = rel_idx[(n0 + 1) * KK + k];
        int e = half ? ei1 : ei0;
        int r = half ? ri1 : ri0;
        float2 rv = *(const float2*)(rel_emb + (long)r * DD + 2 * l);
        float2 tv = *(const float2*)(ent_emb + (long)e * DD + 2 * l);
        tail[k] = tv;
        trp[k] = make_float2(tv.x * rv.x, tv.y * rv.y);
        s2.x = fmaf(rv.x, rv.x, s2.x);
        s2.y = fmaf(rv.y, rv.y, s2.y);
    }
    float2 hn;                          // |head[d]| * sqrt(sum_k rel^2) (ref axis=1 norm)
    hn.x = fabsf(head.x) * sqrtf(s2.x);
    hn.y = fabsf(head.y) * sqrtf(s2.y);

    float att[KK];
#pragma unroll
    for (int k = 0; k < KK; ++k) {
        float v = fmaf(trp[k].y, hn.y, trp[k].x * hn.x);
#pragma unroll
        for (int m = 1; m < 32; m <<= 1)        // stays within each 32-half
            v += __shfl_xor(v, m, 64);
        att[k] = v * v;                          // reference squares the logit
    }
    float mx = att[0];
#pragma unroll
    for (int k = 1; k < KK; ++k) mx = fmaxf(mx, att[k]);
    float den = 0.f;
#pragma unroll
    for (int k = 0; k < KK; ++k) { att[k] = __expf(att[k] - mx); den += att[k]; }
    float inv = 1.f / den;
    float2 o = make_float2(0.f, 0.f);
#pragma unroll
    for (int k = 0; k < KK; ++k) {
        o.x = fmaf(att[k], tail[k].x, o.x);
        o.y = fmaf(att[k], tail[k].y, o.y);
    }
    o.x *= inv; o.y *= inv;
    *(float2*)(outp + (long)(n0 + half) * DD + 2 * l) = o;
}

// ---------------- stage 1b: fp32 -> bf16 (zero-padded rows) ----------------
__global__ __launch_bounds__(256)
void cvt_kernel(const float* __restrict__ src, unsigned short* __restrict__ dst,
                int n_src, int n_total)
{
    int t = blockIdx.x * 256 + threadIdx.x;
    if (t >= n_total) return;
    float v = (t < n_src) ? src[t] : 0.f;
    dst[t] = f2bf(v);
}

// ---------------- stage 1c: transpose newsagg [10000][64] -> AT bf16 [64][10016] ----------------
__global__ __launch_bounds__(256)
void transpose_kernel(const float* __restrict__ src, unsigned short* __restrict__ AT)
{
    __shared__ float T[128][65];
    int t = threadIdx.x;
    int nb = blockIdx.x * 128;
    const float4* s4 = (const float4*)src;
#pragma unroll
    for (int i = 0; i < 8; ++i) {
        int f = i * 256 + t;
        int row = f >> 4;
        int c4 = f & 15;
        int gr = nb + row;
        float4 v = make_float4(0.f, 0.f, 0.f, 0.f);
        if (gr < 10000) v = s4[(long)gr * 16 + c4];
        T[row][c4 * 4 + 0] = v.x;
        T[row][c4 * 4 + 1] = v.y;
        T[row][c4 * 4 + 2] = v.z;
        T[row][c4 * 4 + 3] = v.w;
    }
    __syncthreads();
    int d = t >> 2;
    int seg = t & 3;
#pragma unroll
    for (int g = 0; g < 8; ++g) {
        int nl = seg * 32 + g * 4;
        int n = nb + nl;
        if (n + 3 < ATSTRIDE) {
            ushort4 oh;
            oh.x = f2bf(T[nl + 0][d]);
            oh.y = f2bf(T[nl + 1][d]);
            oh.z = f2bf(T[nl + 2][d]);
            oh.w = f2bf(T[nl + 3][d]);
            *(ushort4*)(AT + (long)d * ATSTRIDE + n) = oh;
        }
    }
}

// ---------------- stage 2: segment-sum via CSR (hist/scan/fill/gather) ----------------
__global__ __launch_bounds__(256)
void hist_kernel(const int* __restrict__ rows, int* __restrict__ cnt, int nnz)
{
    int e = blockIdx.x * 256 + threadIdx.x;
    if (e < nnz) atomicAdd(&cnt[rows[e]], 1);
}

// single block; 256 threads x 40 rows = 10240 >= 10001 needed
__global__ __launch_bounds__(256)
void scan_kernel(const int* __restrict__ cnt, int* __restrict__ offs, int* __restrict__ cur)
{
    __shared__ int ssum[256];
    int t = threadIdx.x;
    int loc[40];
    int s = 0;
#pragma unroll
    for (int i = 0; i < 40; ++i) { loc[i] = s; s += cnt[t * 40 + i]; }
    ssum[t] = s;
    __syncthreads();
    int val = s;
    for (int off = 1; off < 256; off <<= 1) {
        int v = (t >= off) ? ssum[t - off] : 0;
        __syncthreads();
        val += v;
        ssum[t] = val;
        __syncthreads();
    }
    int excl = val - s;
#pragma unroll
    for (int i = 0; i < 40; ++i) {
        int o = excl + loc[i];
        offs[t * 40 + i] = o;
        cur[t * 40 + i] = o;
    }
}

__global__ __launch_bounds__(256)
void fill_kernel(const int* __restrict__ rows, int* __restrict__ cur,
                 int* __restrict__ eid, int nnz)
{
    int e = blockIdx.x * 256 + threadIdx.x;
    if (e < nnz) {
        int p = atomicAdd(&cur[rows[e]], 1);
        eid[p] = e;
    }
}

// one wave per user; zero atomics, plain store
__global__ __launch_bounds__(256)
void gather_kernel(const int* __restrict__ offs, const int* __restrict__ eid,
                   const int* __restrict__ cols, const float* __restrict__ vals,
                   const float* __restrict__ A, float* __restrict__ seg, int n_users)
{
    int w = threadIdx.x >> 6;
    int lane = threadIdx.x & 63;
    int u = blockIdx.x * 4 + w;
    if (u >= n_users) return;
    int s0 = offs[u], s1 = offs[u + 1];
    float acc = 0.f;
    for (int i = s0; i < s1; ++i) {
        int e = eid[i];
        float v = vals[e];
        int c = cols[e];
        acc = fmaf(v, A[(long)c * DD + lane], acc);
    }
    seg[(long)u * DD + lane] = acc;
}

// ---------------- stage 3: bf16 MFMA flash attention, 64 users/wave ----------------
// ONE WAVE = (64-user strip = four 16-row MFMA tiles) x (1-of-20 news slice).
// B/AT fragment loads are shared across 4 tiles -> VMEM halves again vs R8
// (8 KB per 32-news chunk now feeds 64 users). QK is plain bf16; den sums the
// bf16-ROUNDED p so P-quantization cancels num/den at softmax peaks.
// Merge across slices via atomicAdd into zero-initialized num/den.
__global__ __launch_bounds__(256)
void attn_kernel(const unsigned short* __restrict__ Ubf,
                 const unsigned short* __restrict__ Bbf,
                 const unsigned short* __restrict__ ATbf,
                 float* __restrict__ num, float* __restrict__ den)
{
    __shared__ __align__(16) short P[4][4][16 * PSTRIDE];

    int w = threadIdx.x >> 6;
    int lane = threadIdx.x & 63;
    int quad = lane >> 4;
    int l15 = lane & 15;
    int wid = blockIdx.x * 4 + w;
    if (wid >= NSTRIP * NSL) return;
    int strip = wid % NSTRIP;
    int slice = wid / NSTRIP;          // 0..NSL-1
    int user0 = strip * 64;

    // A-frags for the four 16-user tiles
    short8 ua0[4], ua1[4];
#pragma unroll
    for (int t = 0; t < 4; ++t) {
        const short* up = (const short*)Ubf + ((long)(user0 + t * 16 + l15)) * 64;
        ua0[t] = *(const short8*)(up + quad * 8);        // k 0..31
        ua1[t] = *(const short8*)(up + 32 + quad * 8);   // k 32..63
    }

    f32x4 numC[4][4];
    float dena[4][4];
#pragma unroll
    for (int t = 0; t < 4; ++t)
#pragma unroll
        for (int c = 0; c < 4; ++c) {
            numC[t][c] = (f32x4){0.f, 0.f, 0.f, 0.f};
            dena[t][c] = 0.f;
        }

    for (int ch = slice; ch < NCHUNK; ch += NSL) {
        int nb = ch * 32;
        const short* bh = (const short*)Bbf + ((long)(nb + l15)) * 64;
        short8 b00 = *(const short8*)(bh + quad * 8);
        short8 b01 = *(const short8*)(bh + 32 + quad * 8);
        short8 b10 = *(const short8*)(bh + 16 * 64 + quad * 8);
        short8 b11 = *(const short8*)(bh + 16 * 64 + 32 + quad * 8);

        bool vlo = (nb + l15) < 10000;
        bool vhi = (nb + 16 + l15) < 10000;
        f32x4 z = {0.f, 0.f, 0.f, 0.f};
#pragma unroll
        for (int t = 0; t < 4; ++t) {
            f32x4 Llo = MFMA16(ua0[t], b00, z);
            Llo = MFMA16(ua1[t], b01, Llo);
            f32x4 Lhi = MFMA16(ua0[t], b10, z);
            Lhi = MFMA16(ua1[t], b11, Lhi);
            short* Pt = P[w][t];
#pragma unroll
            for (int r = 0; r < 4; ++r) {
                float plo = vlo ? __expf(fminf(Llo[r], 70.f)) : 0.f;
                float phi = vhi ? __expf(fminf(Lhi[r], 70.f)) : 0.f;
                unsigned short qlo = f2bf(plo), qhi = f2bf(phi);
                // C-layout -> LDS: row=quad*4+r, col=l15 (+16 for hi tile)
                Pt[(quad * 4 + r) * PSTRIDE + l15]      = (short)qlo;
                Pt[(quad * 4 + r) * PSTRIDE + 16 + l15] = (short)qhi;
                dena[t][r] += bfu2f(qlo) + bfu2f(qhi);
            }
        }
        // PV: P A-frags from LDS (m120 layout swap), shared V B-frags from AT
        short8 ap[4];
#pragma unroll
        for (int t = 0; t < 4; ++t)
            ap[t] = *(const short8*)(P[w][t] + l15 * PSTRIDE + quad * 8);
#pragma unroll
        for (int c = 0; c < 4; ++c) {
            short8 vh = *(const short8*)((const short*)ATbf +
                        ((long)(16 * c + l15)) * ATSTRIDE + nb + quad * 8);
#pragma unroll
            for (int t = 0; t < 4; ++t)
                numC[t][c] = MFMA16(ap[t], vh, numC[t][c]);
        }
    }

    // den: butterfly over the 16 news-lanes (l15) within each quad
#pragma unroll
    for (int t = 0; t < 4; ++t)
#pragma unroll
        for (int r = 0; r < 4; ++r) {
#pragma unroll
            for (int m = 1; m < 16; m <<= 1)
                dena[t][r] += __shfl_xor(dena[t][r], m, 64);
        }
    if (l15 == 0) {
#pragma unroll
        for (int t = 0; t < 4; ++t)
#pragma unroll
            for (int r = 0; r < 4; ++r)
                atomicAdd(&den[user0 + t * 16 + quad * 4 + r], dena[t][r]);
    }
#pragma unroll
    for (int t = 0; t < 4; ++t)
#pragma unroll
        for (int c = 0; c < 4; ++c)
#pragma unroll
            for (int r = 0; r < 4; ++r)
                atomicAdd(&num[(long)(user0 + t * 16 + quad * 4 + r) * DD + c * 16 + l15],
                          numC[t][c][r]);
}

// ---------------- stage 4: final combine ----------------
__global__ __launch_bounds__(256)
void final_kernel(const float* __restrict__ seg, const float* __restrict__ num,
                  const float* __restrict__ den, float* __restrict__ out, int n_users)
{
    int t = blockIdx.x * 256 + threadIdx.x;
    if (t >= n_users * DD) return;
    int u = t >> 6;
    float s = seg[t];
    float o2 = num[t] / den[u];
    out[t] = fmaf(s, o2, s);
}

extern "C" void kernel_launch(void* const* d_in, const int* in_sizes, int n_in,
                              void* d_out, int out_size, void* d_ws, size_t ws_size,
                              hipStream_t stream)
{
    const float* user_emb = (const float*)d_in[0];
    const float* news_emb = (const float*)d_in[1];
    const float* ent_emb  = (const float*)d_in[2];
    const float* rel_emb  = (const float*)d_in[3];
    const int* news_entities   = (const int*)d_in[4];
    const int* news_relations  = (const int*)d_in[5];
    const int* neigh_entities  = (const int*)d_in[6];
    const int* neigh_relations = (const int*)d_in[7];
    const int* interact_rows   = (const int*)d_in[8];
    const int* interact_cols   = (const int*)d_in[9];
    const float* interact_vals = (const float*)d_in[10];

    const int NU = 10000, NN = 10000, NE = 100000, NNZ = 500000;

    float* out_news = (float*)d_out;
    float* out_ent  = out_news + (long)NN * DD;
    float* out_user = out_ent + (long)NE * DD;

    // Scratch inside the entity-output region (25.6MB; ~11.2MB used).
    // Entity agg runs LAST and overwrites it. No d_ws use.
    float* seg  = out_ent;                           // 640000 f32
    float* num  = seg + 640000;                      // 643072 f32 (10048 users)
    float* den  = num + 643072;                      // 10240 f32
    int*   cnt  = (int*)(den + 10240);               // 10240 i32
    int*   offs = cnt + 10240;                       // 10240 i32
    int*   cur  = offs + 10240;                      // 10240 i32
    int*   eid  = cur + 10240;                       // 500000 i32
    unsigned short* Ubf  = (unsigned short*)(eid + 500000);  // 643072 u16 (16B-aligned)
    unsigned short* Bbf  = Ubf + 643072;             // 641024 u16
    unsigned short* ATbf = Bbf + 641024;             // 641024 u16

    // zero num | den | cnt (contiguous)
    hipMemsetAsync(num, 0, (size_t)(643072 + 10240 + 10240) * sizeof(float), stream);

    // 1) news aggregation -> output 0 (attention K/V source)
    agg_kernel<<<NN / 8, 256, 0, stream>>>(news_emb, ent_emb, rel_emb,
                                           news_entities, news_relations, out_news, NN);
    // 1b) bf16 conversions (U padded to 10048 rows, B to 10016)
    cvt_kernel<<<(NUPAD * DD + 255) / 256, 256, 0, stream>>>(user_emb, Ubf, NU * DD, NUPAD * DD);
    cvt_kernel<<<2504, 256, 0, stream>>>(out_news, Bbf, NN * DD, 10016 * DD);
    transpose_kernel<<<(NN + 127) / 128, 256, 0, stream>>>(out_news, ATbf);
    // 2) segment-sum via CSR: hist -> scan -> fill -> gather (no fp atomics)
    hist_kernel<<<(NNZ + 255) / 256, 256, 0, stream>>>(interact_rows, cnt, NNZ);
    scan_kernel<<<1, 256, 0, stream>>>(cnt, offs, cur);
    fill_kernel<<<(NNZ + 255) / 256, 256, 0, stream>>>(interact_rows, cur, eid, NNZ);
    gather_kernel<<<(NU + 3) / 4, 256, 0, stream>>>(offs, eid, interact_cols,
                                                    interact_vals, out_news, seg, NU);
    // 3) MFMA attention partials: 3140 independent waves (157 strips x 20 slices)
    attn_kernel<<<(NSTRIP * NSL + 3) / 4, 256, 0, stream>>>(Ubf, Bbf, ATbf, num, den);
    // 4) user output
    final_kernel<<<(NU * DD + 255) / 256, 256, 0, stream>>>(seg, num, den, out_user, NU);
    // 5) entity aggregation LAST — overwrites scratch with output 1
    agg_kernel<<<NE / 8, 256, 0, stream>>>(ent_emb, ent_emb, rel_emb,
                                           neigh_entities, neigh_relations, out_ent, NE);
}